// Round 4
// baseline (234.829 us; speedup 1.0000x reference)
//
#include <hip/hip_runtime.h>
#include <hip/hip_bf16.h>

typedef __hip_bfloat16 bf16;
typedef __attribute__((ext_vector_type(8))) short short8;   // 8 bf16, 4 VGPRs
typedef __attribute__((ext_vector_type(4))) short shortx4;  // 4 bf16 (HIP owns "short4")
typedef __attribute__((ext_vector_type(4))) float floatx4;  // MFMA acc

// B=8, T=8192, D=64, M=256, chunk L=64, NCHUNK=1024, NTOK=65536
#define NEED_WS_BYTES 110625024ULL

__device__ __forceinline__ float b2f(bf16 x) { return __bfloat162float(x); }
__device__ __forceinline__ bf16  f2b(float x) { return __float2bfloat16(x); }
__device__ __forceinline__ float bflo(unsigned u) { return __uint_as_float(u << 16); }
__device__ __forceinline__ float bfhi(unsigned u) { return __uint_as_float(u & 0xffff0000u); }

// dtype-dispatched input load: isf32 ? f32 : bf16
__device__ __forceinline__ float ldin(const void* p, size_t i, int isf32) {
  return isf32 ? ((const float*)p)[i] : b2f(((const bf16*)p)[i]);
}

// f32 -> bf16 bits of (f * 0.125)
__device__ __forceinline__ short sb(float f) {
  bf16 h = f2b(f * 0.125f);
  return *reinterpret_cast<short*>(&h);
}
// bf16 bits -> bf16 bits of (x * 0.125) (exact exponent shift)
__device__ __forceinline__ short scale_b(short u) {
  float f = __uint_as_float(((unsigned)(unsigned short)u) << 16) * 0.125f;
  bf16 h = f2b(f);
  return *reinterpret_cast<short*>(&h);
}

// ---- k_detect: decide whether inputs are f32 or bf16 -----------------------
__global__ __launch_bounds__(256) void k_detect(const void* __restrict__ q,
                                                int* __restrict__ flag) {
  __shared__ int cnt;
  if (threadIdx.x == 0) cnt = 0;
  __syncthreads();
  const unsigned short* u = (const unsigned short*)q;
  int c = 0;
  for (int e = threadIdx.x; e < 2048; e += 256) {
    unsigned short w = u[2 * e];
    int ex = (w >> 7) & 0xFF;
    if ((w & 0x7FFF) != 0 && (ex < 110 || ex > 140)) c++;
  }
  atomicAdd(&cnt, c);
  __syncthreads();
  if (threadIdx.x == 0) *flag = (cnt > 512) ? 1 : 0;
}

// ---- k_omega: convert omega -> bf16 copy -----------------------------------
__global__ __launch_bounds__(256) void k_omega(const void* __restrict__ omega,
                                               bf16* __restrict__ omb,
                                               const int* __restrict__ flag) {
  int isf32 = *flag;
  int e = blockIdx.x * 256 + threadIdx.x;
  omb[e] = f2b(ldin(omega, e, isf32));
}

// ---- k_phi (MFMA): dot = x@omega^T via mfma_f32_16x16x32_bf16 --------------
// (-0.5||x||^2 cancels exactly under the rowmax subtraction; omitted.)
// R3: split output staging into 2 half-passes -> LDS 33.8K -> 17.4K. Theory:
// occupancy was stuck at ~8 waves/CU (24.6%) despite 33.8K*4 < 160K; if LDS
// granularity capped blocks at 2, halving doubles blocks -> 16 waves/CU.
// Layouts (m89/m91-verified): A[m=lane&15][k=quad*8+j], B[n=lane&15][k=quad*8+j],
// C: col=lane&15, row=quad*4+reg.
__global__ __launch_bounds__(256)
__attribute__((amdgpu_waves_per_eu(1, 4))) void k_phi(
    const void* __restrict__ q, const void* __restrict__ k,
    const bf16* __restrict__ omb, bf16* __restrict__ phiQ,
    bf16* __restrict__ phiK, const int* __restrict__ flag) {
  __shared__ short ob[4][16][136];   // per-wave half-tile (128 feat + 8 pad)
  int isf32 = *flag;
  int tid = threadIdx.x;
  int isK = blockIdx.y;
  const void* src = isK ? k : q;
  bf16* dst = isK ? phiK : phiQ;
  size_t tok0 = (size_t)blockIdx.x * 64;

  int li = tid & 15;
  int quad = (tid >> 4) & 3;
  int w = tid >> 6;               // wave id -> token block m0
  int m0 = w * 16;
  size_t row = tok0 + m0 + li;    // this lane's token row

  // ---- a-frags straight from global (scaled f32/bf16 -> bf16 in regs) ------
  short8 a0, a1;
  if (isf32) {
    const float* xr = (const float*)src + row * 64;
    float4 f0 = *reinterpret_cast<const float4*>(xr + quad * 8);
    float4 f1 = *reinterpret_cast<const float4*>(xr + quad * 8 + 4);
    float4 f2 = *reinterpret_cast<const float4*>(xr + 32 + quad * 8);
    float4 f3 = *reinterpret_cast<const float4*>(xr + 32 + quad * 8 + 4);
    a0[0] = sb(f0.x); a0[1] = sb(f0.y); a0[2] = sb(f0.z); a0[3] = sb(f0.w);
    a0[4] = sb(f1.x); a0[5] = sb(f1.y); a0[6] = sb(f1.z); a0[7] = sb(f1.w);
    a1[0] = sb(f2.x); a1[1] = sb(f2.y); a1[2] = sb(f2.z); a1[3] = sb(f2.w);
    a1[4] = sb(f3.x); a1[5] = sb(f3.y); a1[6] = sb(f3.z); a1[7] = sb(f3.w);
  } else {
    const short* xr = (const short*)src + row * 64;
    short8 r0 = *reinterpret_cast<const short8*>(xr + quad * 8);
    short8 r1 = *reinterpret_cast<const short8*>(xr + 32 + quad * 8);
    #pragma unroll
    for (int j = 0; j < 8; ++j) { a0[j] = scale_b(r0[j]); a1[j] = scale_b(r1[j]); }
  }

  // ---- 16 n0-tiles x 2 K-halves = 32 MFMA; omega rows from L2 --------------
  floatx4 c[16];
  #pragma unroll
  for (int n0 = 0; n0 < 16; ++n0) {
    const short* bp = (const short*)omb + (size_t)(n0 * 16 + li) * 64 + quad * 8;
    short8 b0 = *reinterpret_cast<const short8*>(bp);
    short8 b1 = *reinterpret_cast<const short8*>(bp + 32);
    floatx4 acc = {0.f, 0.f, 0.f, 0.f};
    acc = __builtin_amdgcn_mfma_f32_16x16x32_bf16(a0, b0, acc, 0, 0, 0);
    acc = __builtin_amdgcn_mfma_f32_16x16x32_bf16(a1, b1, acc, 0, 0, 0);
    c[n0] = acc;
  }

  // ---- rowmax over 256 features: 16-tile local max + 16-lane butterfly -----
  float mx[4];
  #pragma unroll
  for (int r = 0; r < 4; ++r) {
    float m = c[0][r];
    #pragma unroll
    for (int n0 = 1; n0 < 16; ++n0) m = fmaxf(m, c[n0][r]);
    mx[r] = m;
  }
  #pragma unroll
  for (int mask = 1; mask < 16; mask <<= 1) {
    #pragma unroll
    for (int r = 0; r < 4; ++r) mx[r] = fmaxf(mx[r], __shfl_xor(mx[r], mask, 64));
  }

  // ---- exp -> wave-private LDS half-tile -> coalesced 16B store, 2 passes --
  size_t srow = tok0 + m0 + li;
  #pragma unroll
  for (int h = 0; h < 2; ++h) {
    #pragma unroll
    for (int r = 0; r < 4; ++r) {
      #pragma unroll
      for (int n = 0; n < 8; ++n) {
        bf16 hv = f2b(__expf(c[h * 8 + n][r] - mx[r]) * 0.0625f);  // 1/sqrt(256)
        ob[w][quad * 4 + r][n * 16 + li] = *reinterpret_cast<short*>(&hv);
      }
    }
    // lane (quad,li) -> row li, 16B chunk (it*4+quad) of this half
    #pragma unroll
    for (int it = 0; it < 4; ++it) {
      int ch = it * 4 + quad;
      short8 vv = *reinterpret_cast<const short8*>(&ob[w][li][ch * 8]);
      *reinterpret_cast<short8*>((short*)dst + srow * 256 + h * 128 + ch * 8) = vv;
    }
  }
}

// ---- k_slocal: per-chunk S^T (d x i, TRANSPOSED) bf16 and z f32 ------------
// SlocT[chunk][d][i] = sum_t phiK[t][i] * V[t][d].
// R3: stage phiK chunk in LDS (straight short8 copy). Inner loop's pk read was
// a scalar global column walk (stride 512B, ~200-900cy each, gating every t);
// now ds_read_u16 (2-way conflict, ~6cy). Latency-bound 55us -> VALU-bound.
__global__ __launch_bounds__(256) void k_slocal(
    const bf16* __restrict__ phiK, const void* __restrict__ v,
    bf16* __restrict__ SlocT, float* __restrict__ zloc,
    const int* __restrict__ flag) {
  __shared__ float vs[64 * 64];      // 16 KB
  __shared__ short pks[64 * 256];    // 32 KB phiK chunk [t][i]
  int isf32 = *flag;
  int chunk = blockIdx.x;
  size_t tok0 = (size_t)chunk * 64;
  int tid = threadIdx.x;
  for (int e = tid; e < 4096; e += 256) vs[e] = ldin(v, tok0 * 64 + e, isf32);
  {
    const short* src = (const short*)phiK + tok0 * 256;
    #pragma unroll
    for (int it = 0; it < 8; ++it) {
      int e8 = it * 256 + tid;
      *reinterpret_cast<short8*>(&pks[e8 * 8]) =
          *reinterpret_cast<const short8*>(src + e8 * 8);
    }
  }
  __syncthreads();
  int i = tid;
  float acc[64];
  #pragma unroll
  for (int jj = 0; jj < 64; ++jj) acc[jj] = 0.f;
  float az = 0.f;
  #pragma unroll 2
  for (int t = 0; t < 64; ++t) {
    float pk = bflo((unsigned)(unsigned short)pks[t * 256 + i]);
    az += pk;
    const float* vr = vs + t * 64;
    #pragma unroll
    for (int jj = 0; jj < 64; ++jj) acc[jj] += pk * vr[jj];
  }
  bf16* Sb = SlocT + (size_t)chunk * 16384 + i;
  #pragma unroll
  for (int jj = 0; jj < 64; ++jj) Sb[(size_t)jj * 256] = f2b(acc[jj]);
  zloc[(size_t)chunk * 256 + i] = az;
}

// ---- k_sprefix: in-place exclusive prefix of SlocT over chunks (bf16) ------
// R3: was float vbuf[128] = 128 VGPRs -> scratch spill. Now short2-vectorized
// streaming in tiles of 16 (VGPR ~24, 4B/lane coalesced loads). Elementwise
// over each chunk's 16384 elems -> layout-agnostic, bit-identical results.
__global__ __launch_bounds__(64) void k_sprefix(bf16* __restrict__ SlocT) {
  int b = blockIdx.x >> 7, g = blockIdx.x & 127;
  int p = g * 64 + threadIdx.x;                 // short2 column index [0,8192)
  unsigned* base = (unsigned*)(SlocT + (size_t)b * 2097152) + p;  // +8192/chunk
  float r0 = 0.f, r1 = 0.f;
  #pragma unroll 1
  for (int g16 = 0; g16 < 8; ++g16) {
    unsigned vb[16];
    #pragma unroll
    for (int j = 0; j < 16; ++j) vb[j] = base[(size_t)(g16 * 16 + j) * 8192];
    #pragma unroll
    for (int j = 0; j < 16; ++j) {
      unsigned u = vb[j];
      float t0 = bflo(u), t1 = bfhi(u);
      bf16 h0 = f2b(r0), h1 = f2b(r1);
      vb[j] = ((unsigned)*(unsigned short*)&h0) |
              (((unsigned)*(unsigned short*)&h1) << 16);
      r0 += t0; r1 += t1;
    }
    #pragma unroll
    for (int j = 0; j < 16; ++j) base[(size_t)(g16 * 16 + j) * 8192] = vb[j];
  }
}

// ---- k_zprefix: in-place exclusive prefix of zloc over chunks (f32) --------
// R3: same spill fix (was vbuf[128]); tile-16 streaming.
__global__ __launch_bounds__(64) void k_zprefix(float* __restrict__ zloc) {
  int b = blockIdx.x >> 2, ig = blockIdx.x & 3;
  int i = ig * 64 + threadIdx.x;
  float* base = zloc + (size_t)b * 32768 + i;
  float run = 0.f;
  #pragma unroll 1
  for (int g16 = 0; g16 < 8; ++g16) {
    float vb[16];
    #pragma unroll
    for (int j = 0; j < 16; ++j) vb[j] = base[(size_t)(g16 * 16 + j) * 256];
    #pragma unroll
    for (int j = 0; j < 16; ++j) { float t = vb[j]; vb[j] = run; run += t; }
    #pragma unroll
    for (int j = 0; j < 16; ++j) base[(size_t)(g16 * 16 + j) * 256] = vb[j];
  }
}

// ---- k_out (MFMA): out[t] = (phiQ@Sp + tril(A)@V) / (phiQ.zp + rowsum + eps)
// 1024 blocks x 4 waves; wave w owns m-tile (rows m0=w*16 .. +15).
//   mm1: A = phiQ @ phiK^T (K=256), triangular (n0 <= w only), masked in-reg,
//        rowsum den-partials, bf16 A -> wave-private LDS rows.
//   mm2: out1 = phiQ @ Sp   (K=256), b-frags = SpT LDS rows.
//   mm3: out2 = trilA @ V   (K=64),  V split hi+lo bf16.
// LDS 61440 B -> 2 blocks/CU; waves_per_eu(1,2) (spill tripwire R5-R11).
__global__ __launch_bounds__(256)
__attribute__((amdgpu_waves_per_eu(1, 2))) void k_out(
    const bf16* __restrict__ phiQ, const bf16* __restrict__ phiK,
    const void* __restrict__ v, const bf16* __restrict__ SlocT,
    const float* __restrict__ zloc, void* __restrict__ outp,
    const int* __restrict__ flag) {
  __shared__ short spT[64 * 264];   // SpT[d][i], pad 8     33792 B
  __shared__ short vTh[64 * 72];    // V^T hi bf16           9216 B
  __shared__ short vTl[64 * 72];    // V^T lo bf16           9216 B
  __shared__ short aT[64 * 72];     // masked A[t][tau]      9216 B

  int isf32 = *flag;
  int chunk = blockIdx.x;
  size_t tok0 = (size_t)chunk * 64;
  int tid = threadIdx.x;
  int lane = tid & 63;
  int li = lane & 15;
  int quad = lane >> 4;
  int w = __builtin_amdgcn_readfirstlane(tid >> 6);  // wave id = m-tile
  int m0 = w * 16;

  // ---- stage SpT: straight 16B copy of this chunk's exclusive-prefix S^T ---
  {
    const short* src = (const short*)SlocT + (size_t)chunk * 16384;
    #pragma unroll
    for (int it = 0; it < 8; ++it) {
      int e = it * 256 + tid;
      int d = e >> 5, seg = e & 31;
      *reinterpret_cast<short8*>(&spT[d * 264 + seg * 8]) =
          *reinterpret_cast<const short8*>(src + d * 256 + seg * 8);
    }
  }
  // ---- stage V^T split hi/lo (coalesced f32 reads; lo==0 for bf16 input) ---
  #pragma unroll
  for (int it = 0; it < 16; ++it) {
    int e = it * 256 + tid;
    int tau = e >> 6, d = e & 63;
    float vv = ldin(v, tok0 * 64 + e, isf32);
    bf16 h = f2b(vv);
    bf16 l = f2b(vv - b2f(h));
    vTh[d * 72 + tau] = *reinterpret_cast<short*>(&h);
    vTl[d * 72 + tau] = *reinterpret_cast<short*>(&l);
  }
  // ---- zero own above-diagonal A region (rows wave-private: no race) -------
  {
    shortx4 z4 = {0, 0, 0, 0};
    int row = m0 + li;
    for (int c = (w + 1) * 16 + quad * 4; c < 64; c += 16)
      *reinterpret_cast<shortx4*>(&aT[row * 72 + c]) = z4;
  }

  // ---- a1-frags: phiQ rows of this m-tile (L2-hot; reused mm1+mm2) ---------
  const short* pqf = (const short*)phiQ + (tok0 + m0 + li) * 256 + quad * 8;
  short8 a1[8];
  #pragma unroll
  for (int kk = 0; kk < 8; ++kk)
    a1[kk] = *reinterpret_cast<const short8*>(pqf + kk * 32);

  // ---- mm1: A tiles, n0 <= w only (tiles above diagonal are all-masked) ----
  floatx4 c1[4];
  #pragma unroll
  for (int n0 = 0; n0 < 4; ++n0) c1[n0] = (floatx4){0.f, 0.f, 0.f, 0.f};
  const short* pkb = (const short*)phiK + tok0 * 256;
  #pragma unroll
  for (int n0 = 0; n0 < 4; ++n0) {
    if (n0 <= w) {
      const short* bp = pkb + (size_t)(n0 * 16 + li) * 256 + quad * 8;
      floatx4 acc = c1[n0];
      #pragma unroll
      for (int kk = 0; kk < 8; ++kk) {
        short8 b = *reinterpret_cast<const short8*>(bp + kk * 32);
        acc = __builtin_amdgcn_mfma_f32_16x16x32_bf16(a1[kk], b, acc, 0, 0, 0);
      }
      c1[n0] = acc;
    }
  }

  // ---- tril mask + den rowsum partials + write bf16 A to own LDS rows ------
  float dpart[4] = {0.f, 0.f, 0.f, 0.f};
  #pragma unroll
  for (int n0 = 0; n0 < 4; ++n0) {
    if (n0 <= w) {
      int tau = n0 * 16 + li;
      #pragma unroll
      for (int r = 0; r < 4; ++r) {
        int t = m0 + quad * 4 + r;
        float val = (tau <= t) ? c1[n0][r] : 0.f;
        dpart[r] += val;
        bf16 hh = f2b(val);
        aT[t * 72 + tau] = *reinterpret_cast<short*>(&hh);
      }
    }
  }

  __syncthreads();   // spT/vTh/vTl ready (aT is wave-private: own rows only)

  // ---- mm2 (phiQ @ Sp) + mm3 (trilA @ Vhi + trilA @ Vlo), shared acc -------
  floatx4 o[4];
  #pragma unroll
  for (int n0 = 0; n0 < 4; ++n0) o[n0] = (floatx4){0.f, 0.f, 0.f, 0.f};

  const short* arow = &aT[(m0 + li) * 72 + quad * 8];
  short8 a3_0 = *reinterpret_cast<const short8*>(arow);
  short8 a3_1 = *reinterpret_cast<const short8*>(arow + 32);

  #pragma unroll
  for (int n0 = 0; n0 < 4; ++n0) {
    floatx4 acc = o[n0];
    const short* sp = &spT[(n0 * 16 + li) * 264 + quad * 8];
    #pragma unroll
    for (int kk = 0; kk < 8; ++kk) {
      short8 b = *reinterpret_cast<const short8*>(sp + kk * 32);
      acc = __builtin_amdgcn_mfma_f32_16x16x32_bf16(a1[kk], b, acc, 0, 0, 0);
    }
    const short* vph = &vTh[(n0 * 16 + li) * 72 + quad * 8];
    const short* vpl = &vTl[(n0 * 16 + li) * 72 + quad * 8];
    short8 bh0 = *reinterpret_cast<const short8*>(vph);
    short8 bh1 = *reinterpret_cast<const short8*>(vph + 32);
    short8 bl0 = *reinterpret_cast<const short8*>(vpl);
    short8 bl1 = *reinterpret_cast<const short8*>(vpl + 32);
    acc = __builtin_amdgcn_mfma_f32_16x16x32_bf16(a3_0, bh0, acc, 0, 0, 0);
    acc = __builtin_amdgcn_mfma_f32_16x16x32_bf16(a3_1, bh1, acc, 0, 0, 0);
    acc = __builtin_amdgcn_mfma_f32_16x16x32_bf16(a3_0, bl0, acc, 0, 0, 0);
    acc = __builtin_amdgcn_mfma_f32_16x16x32_bf16(a3_1, bl1, acc, 0, 0, 0);
    o[n0] = acc;
  }

  // ---- den: dpart += pq . zp  (lane li covers i in [li*16, li*16+16)) ------
  {
    const floatx4* zp4 =
        reinterpret_cast<const floatx4*>(zloc + (size_t)chunk * 256 + li * 16);
    floatx4 z0 = zp4[0], z1 = zp4[1], z2 = zp4[2], z3 = zp4[3];
    #pragma unroll
    for (int r = 0; r < 4; ++r) {
      const short* pqr =
          (const short*)phiQ + (tok0 + m0 + quad * 4 + r) * 256 + li * 16;
      short8 p0 = *reinterpret_cast<const short8*>(pqr);
      short8 p1 = *reinterpret_cast<const short8*>(pqr + 8);
      float s = dpart[r];
      #pragma unroll
      for (int j = 0; j < 4; ++j) s += bflo((unsigned short)p0[j]) * z0[j];
      #pragma unroll
      for (int j = 0; j < 4; ++j) s += bflo((unsigned short)p0[4 + j]) * z1[j];
      #pragma unroll
      for (int j = 0; j < 4; ++j) s += bflo((unsigned short)p1[j]) * z2[j];
      #pragma unroll
      for (int j = 0; j < 4; ++j) s += bflo((unsigned short)p1[4 + j]) * z3[j];
      dpart[r] = s;
    }
  }
  // butterfly over the quad's 16 lanes: every lane gets full den for its rows
  #pragma unroll
  for (int mask = 1; mask < 16; mask <<= 1) {
    #pragma unroll
    for (int r = 0; r < 4; ++r) dpart[r] += __shfl_xor(dpart[r], mask, 64);
  }

  // ---- epilogue: out[t][d] = (out1+out2) / (den + eps) ---------------------
  #pragma unroll
  for (int r = 0; r < 4; ++r) {
    float rd = 1.f / (dpart[r] + 1e-6f);
    size_t ob = (tok0 + m0 + quad * 4 + r) * 64 + li;
    if (isf32) {
      float* op = (float*)outp + ob;
      #pragma unroll
      for (int n0 = 0; n0 < 4; ++n0) op[n0 * 16] = o[n0][r] * rd;
    } else {
      bf16* op = (bf16*)outp + ob;
      #pragma unroll
      for (int n0 = 0; n0 < 4; ++n0) op[n0 * 16] = f2b(o[n0][r] * rd);
    }
  }
}

extern "C" void kernel_launch(void* const* d_in, const int* in_sizes, int n_in,
                              void* d_out, int out_size, void* d_ws, size_t ws_size,
                              hipStream_t stream) {
  (void)in_sizes; (void)n_in; (void)out_size;
  if (ws_size < NEED_WS_BYTES) return;   // diagnostic guard

  const void* q = d_in[0];
  const void* k = d_in[1];
  const void* v = d_in[2];
  const void* omega = d_in[3];

  int*   flag = (int*)d_ws;
  float* wsf  = (float*)d_ws + 64;       // data starts 256 B in
  bf16*  omb  = (bf16*)wsf;              // 16384 bf16
  float* zloc = wsf + 131072;            // 1024*256 f32
  bf16*  Sloc = (bf16*)(wsf + 393216);   // 1024*256*64 bf16 (TRANSPOSED [d][i])
  bf16*  phiQ = (bf16*)(wsf + 8781824);  // 65536*256 bf16
  bf16*  phiK = (bf16*)(wsf + 17170432); // 65536*256 bf16

  k_detect<<<1, 256, 0, stream>>>(q, flag);
  k_omega<<<64, 256, 0, stream>>>(omega, omb, flag);
  k_phi<<<dim3(1024, 2), 256, 0, stream>>>(q, k, omb, phiQ, phiK, flag);
  k_slocal<<<1024, 256, 0, stream>>>(phiK, v, Sloc, zloc, flag);
  k_sprefix<<<1024, 64, 0, stream>>>(Sloc);
  k_zprefix<<<32, 64, 0, stream>>>(zloc);
  k_out<<<1024, 256, 0, stream>>>(phiQ, phiK, v, Sloc, zloc, d_out, flag);
}

// Round 5
// 211.124 us; speedup vs baseline: 1.1123x; 1.1123x over previous
//
#include <hip/hip_runtime.h>
#include <hip/hip_bf16.h>

typedef __hip_bfloat16 bf16;
typedef __attribute__((ext_vector_type(8))) short short8;   // 8 bf16, 4 VGPRs
typedef __attribute__((ext_vector_type(4))) short shortx4;  // 4 bf16 (HIP owns "short4")
typedef __attribute__((ext_vector_type(4))) float floatx4;  // MFMA acc

// B=8, T=8192, D=64, M=256, chunk L=64, NCHUNK=1024, NTOK=65536
#define NEED_WS_BYTES 110625024ULL

__device__ __forceinline__ float b2f(bf16 x) { return __bfloat162float(x); }
__device__ __forceinline__ bf16  f2b(float x) { return __float2bfloat16(x); }
__device__ __forceinline__ float bflo(unsigned u) { return __uint_as_float(u << 16); }
__device__ __forceinline__ float bfhi(unsigned u) { return __uint_as_float(u & 0xffff0000u); }

// dtype-dispatched input load: isf32 ? f32 : bf16
__device__ __forceinline__ float ldin(const void* p, size_t i, int isf32) {
  return isf32 ? ((const float*)p)[i] : b2f(((const bf16*)p)[i]);
}

// f32 -> bf16 bits of (f * 0.125)
__device__ __forceinline__ short sb(float f) {
  bf16 h = f2b(f * 0.125f);
  return *reinterpret_cast<short*>(&h);
}
// bf16 bits -> bf16 bits of (x * 0.125) (exact exponent shift)
__device__ __forceinline__ short scale_b(short u) {
  float f = __uint_as_float(((unsigned)(unsigned short)u) << 16) * 0.125f;
  bf16 h = f2b(f);
  return *reinterpret_cast<short*>(&h);
}

// ---- k_detect: decide whether inputs are f32 or bf16 -----------------------
__global__ __launch_bounds__(256) void k_detect(const void* __restrict__ q,
                                                int* __restrict__ flag) {
  __shared__ int cnt;
  if (threadIdx.x == 0) cnt = 0;
  __syncthreads();
  const unsigned short* u = (const unsigned short*)q;
  int c = 0;
  for (int e = threadIdx.x; e < 2048; e += 256) {
    unsigned short w = u[2 * e];
    int ex = (w >> 7) & 0xFF;
    if ((w & 0x7FFF) != 0 && (ex < 110 || ex > 140)) c++;
  }
  atomicAdd(&cnt, c);
  __syncthreads();
  if (threadIdx.x == 0) *flag = (cnt > 512) ? 1 : 0;
}

// ---- k_omega: convert omega -> bf16 copy -----------------------------------
__global__ __launch_bounds__(256) void k_omega(const void* __restrict__ omega,
                                               bf16* __restrict__ omb,
                                               const int* __restrict__ flag) {
  int isf32 = *flag;
  int e = blockIdx.x * 256 + threadIdx.x;
  omb[e] = f2b(ldin(omega, e, isf32));
}

// ---- shared phi helpers ----------------------------------------------------
// Layouts (m89/m91-verified): A[m=lane&15][k=quad*8+j], B[n=lane&15][k=quad*8+j],
// C: col=lane&15 (n-dim), row=quad*4+reg (m-dim).
__device__ __forceinline__ void phi_load_a(const void* src, size_t row, int quad,
                                           int isf32, short8& a0, short8& a1) {
  if (isf32) {
    const float* xr = (const float*)src + row * 64;
    float4 f0 = *reinterpret_cast<const float4*>(xr + quad * 8);
    float4 f1 = *reinterpret_cast<const float4*>(xr + quad * 8 + 4);
    float4 f2 = *reinterpret_cast<const float4*>(xr + 32 + quad * 8);
    float4 f3 = *reinterpret_cast<const float4*>(xr + 32 + quad * 8 + 4);
    a0[0] = sb(f0.x); a0[1] = sb(f0.y); a0[2] = sb(f0.z); a0[3] = sb(f0.w);
    a0[4] = sb(f1.x); a0[5] = sb(f1.y); a0[6] = sb(f1.z); a0[7] = sb(f1.w);
    a1[0] = sb(f2.x); a1[1] = sb(f2.y); a1[2] = sb(f2.z); a1[3] = sb(f2.w);
    a1[4] = sb(f3.x); a1[5] = sb(f3.y); a1[6] = sb(f3.z); a1[7] = sb(f3.w);
  } else {
    const short* xr = (const short*)src + row * 64;
    short8 r0 = *reinterpret_cast<const short8*>(xr + quad * 8);
    short8 r1 = *reinterpret_cast<const short8*>(xr + 32 + quad * 8);
    #pragma unroll
    for (int j = 0; j < 8; ++j) { a0[j] = scale_b(r0[j]); a1[j] = scale_b(r1[j]); }
  }
}

__device__ __forceinline__ void phi_mfma(const bf16* omb, int li, int quad,
                                         const short8& a0, const short8& a1,
                                         floatx4* c, float* mx) {
  #pragma unroll
  for (int n0 = 0; n0 < 16; ++n0) {
    const short* bp = (const short*)omb + (size_t)(n0 * 16 + li) * 64 + quad * 8;
    short8 b0 = *reinterpret_cast<const short8*>(bp);
    short8 b1 = *reinterpret_cast<const short8*>(bp + 32);
    floatx4 acc = {0.f, 0.f, 0.f, 0.f};
    acc = __builtin_amdgcn_mfma_f32_16x16x32_bf16(a0, b0, acc, 0, 0, 0);
    acc = __builtin_amdgcn_mfma_f32_16x16x32_bf16(a1, b1, acc, 0, 0, 0);
    c[n0] = acc;
  }
  #pragma unroll
  for (int r = 0; r < 4; ++r) {
    float m = c[0][r];
    #pragma unroll
    for (int n0 = 1; n0 < 16; ++n0) m = fmaxf(m, c[n0][r]);
    mx[r] = m;
  }
  #pragma unroll
  for (int mask = 1; mask < 16; mask <<= 1) {
    #pragma unroll
    for (int r = 0; r < 4; ++r) mx[r] = fmaxf(mx[r], __shfl_xor(mx[r], mask, 64));
  }
}

// ---- k_phiq: phiQ only (R2 structure: no input LDS, ob-coalesced store) ----
__global__ __launch_bounds__(256)
__attribute__((amdgpu_waves_per_eu(1, 4))) void k_phiq(
    const void* __restrict__ q, const bf16* __restrict__ omb,
    bf16* __restrict__ phiQ, const int* __restrict__ flag) {
  __shared__ short ob[4][16][136];   // per-wave half-tile (128 feat + 8 pad)
  int isf32 = *flag;
  int tid = threadIdx.x;
  size_t tok0 = (size_t)blockIdx.x * 64;
  int li = tid & 15;
  int quad = (tid >> 4) & 3;
  int w = tid >> 6;
  int m0 = w * 16;
  size_t row = tok0 + m0 + li;

  short8 a0, a1;
  phi_load_a(q, row, quad, isf32, a0, a1);
  floatx4 c[16];
  float mx[4];
  phi_mfma(omb, li, quad, a0, a1, c, mx);

  size_t srow = tok0 + m0 + li;
  #pragma unroll
  for (int h = 0; h < 2; ++h) {
    #pragma unroll
    for (int r = 0; r < 4; ++r) {
      #pragma unroll
      for (int n = 0; n < 8; ++n) {
        bf16 hv = f2b(__expf(c[h * 8 + n][r] - mx[r]) * 0.0625f);  // 1/sqrt(256)
        ob[w][quad * 4 + r][n * 16 + li] = *reinterpret_cast<short*>(&hv);
      }
    }
    #pragma unroll
    for (int it = 0; it < 4; ++it) {
      int ch = it * 4 + quad;
      short8 vv = *reinterpret_cast<const short8*>(&ob[w][li][ch * 8]);
      *reinterpret_cast<short8*>((short*)phiQ + srow * 256 + h * 128 + ch * 8) = vv;
    }
  }
}

// ---- k_phik (R5): phiK + fused S^T/z (replaces old k_phi-K + k_slocal) -----
// Phase 1: phi via MFMA (as k_phiq), storing phiK to global AND transposed
//          pkT[i][t] in LDS; z partials from the ROUNDED bf16 values (matches
//          old k_slocal which summed stored bf16 phiK).
// Phase 2 (after 1 barrier): SlocT[d][i] = sum_t V[t][d]*phiK[t][i] via MFMA:
//          A = V^T (hi+lo bf16 split = f32-accurate), B = pkT rows.
//          Wave w owns features i in [w*64, w*64+64): 4 m-tiles x 4 n-tiles,
//          K=64 -> 2 k-steps, x2 hi/lo = 64 MFMA/wave.
// pkT/vT stride 72 shorts: same dword-bank pattern (4(li+quad) mod 32) as
// k_out's working spT reads. LDS total 76.8 KB -> 2 blocks/CU.
__global__ __launch_bounds__(256)
__attribute__((amdgpu_waves_per_eu(1, 2))) void k_phik(
    const void* __restrict__ k, const void* __restrict__ v,
    const bf16* __restrict__ omb, bf16* __restrict__ phiK,
    bf16* __restrict__ SlocT, float* __restrict__ zloc,
    const int* __restrict__ flag) {
  __shared__ short ob[4][16][136];   // 17408 B  per-wave store tile
  __shared__ short pkT[256 * 72];    // 36864 B  phiK^T [i][t]
  __shared__ short vTh[64 * 72];     //  9216 B  V^T hi
  __shared__ short vTl[64 * 72];     //  9216 B  V^T lo
  __shared__ float zpart[4][256];    //  4096 B  per-wave z partials

  int isf32 = *flag;
  int tid = threadIdx.x;
  size_t tok0 = (size_t)blockIdx.x * 64;
  int li = tid & 15;
  int quad = (tid >> 4) & 3;
  int w = tid >> 6;
  int m0 = w * 16;
  size_t row = tok0 + m0 + li;

  // ---- stage V^T hi/lo (coalesced global reads, scalar LDS writes) --------
  #pragma unroll
  for (int it = 0; it < 16; ++it) {
    int e = it * 256 + tid;
    int tau = e >> 6, d = e & 63;
    float vv = ldin(v, tok0 * 64 + e, isf32);
    bf16 h = f2b(vv);
    bf16 l = f2b(vv - b2f(h));
    vTh[d * 72 + tau] = *reinterpret_cast<short*>(&h);
    vTl[d * 72 + tau] = *reinterpret_cast<short*>(&l);
  }

  // ---- phi compute ---------------------------------------------------------
  short8 a0, a1;
  phi_load_a(k, row, quad, isf32, a0, a1);
  floatx4 c[16];
  float mx[4];
  phi_mfma(omb, li, quad, a0, a1, c, mx);

  // ---- exp -> ob (coalesced global store) + pkT (transposed) + z partials --
  float zl[16];
  #pragma unroll
  for (int f = 0; f < 16; ++f) zl[f] = 0.f;
  size_t srow = tok0 + m0 + li;
  #pragma unroll
  for (int h = 0; h < 2; ++h) {
    #pragma unroll
    for (int r = 0; r < 4; ++r) {
      #pragma unroll
      for (int n = 0; n < 8; ++n) {
        bf16 hv = f2b(__expf(c[h * 8 + n][r] - mx[r]) * 0.0625f);  // 1/sqrt(256)
        short hb = *reinterpret_cast<short*>(&hv);
        ob[w][quad * 4 + r][n * 16 + li] = hb;
        pkT[((h * 8 + n) * 16 + li) * 72 + (m0 + quad * 4 + r)] = hb;
        zl[h * 8 + n] += bflo((unsigned)(unsigned short)hb);  // rounded value
      }
    }
    #pragma unroll
    for (int it = 0; it < 4; ++it) {
      int ch = it * 4 + quad;
      short8 vv = *reinterpret_cast<const short8*>(&ob[w][li][ch * 8]);
      *reinterpret_cast<short8*>((short*)phiK + srow * 256 + h * 128 + ch * 8) = vv;
    }
  }
  // z: reduce each feature over this wave's 16 tokens (4 quads x 4 r)
  #pragma unroll
  for (int f = 0; f < 16; ++f) {
    float vz = zl[f];
    vz += __shfl_xor(vz, 16, 64);
    vz += __shfl_xor(vz, 32, 64);
    if (quad == 0) zpart[w][f * 16 + li] = vz;
  }

  __syncthreads();   // pkT, vTh/vTl, zpart ready

  // ---- S GEMM: wave w -> features [w*64, w*64+64), all d ------------------
  int wbase = w * 64;
  floatx4 sa[4][4];
  #pragma unroll
  for (int mt = 0; mt < 4; ++mt)
    #pragma unroll
    for (int n0 = 0; n0 < 4; ++n0) sa[mt][n0] = (floatx4){0.f, 0.f, 0.f, 0.f};

  #pragma unroll
  for (int h = 0; h < 2; ++h) {
    short8 Ah[4], Al[4];
    #pragma unroll
    for (int mt = 0; mt < 4; ++mt) {
      Ah[mt] = *reinterpret_cast<const short8*>(
          &vTh[(mt * 16 + li) * 72 + h * 32 + quad * 8]);
      Al[mt] = *reinterpret_cast<const short8*>(
          &vTl[(mt * 16 + li) * 72 + h * 32 + quad * 8]);
    }
    #pragma unroll
    for (int n0 = 0; n0 < 4; ++n0) {
      short8 Bq = *reinterpret_cast<const short8*>(
          &pkT[(wbase + n0 * 16 + li) * 72 + h * 32 + quad * 8]);
      #pragma unroll
      for (int mt = 0; mt < 4; ++mt) {
        sa[mt][n0] =
            __builtin_amdgcn_mfma_f32_16x16x32_bf16(Ah[mt], Bq, sa[mt][n0], 0, 0, 0);
        sa[mt][n0] =
            __builtin_amdgcn_mfma_f32_16x16x32_bf16(Al[mt], Bq, sa[mt][n0], 0, 0, 0);
      }
    }
  }

  // ---- store S^T (bf16) ----------------------------------------------------
  bf16* Sb = SlocT + (size_t)blockIdx.x * 16384;
  #pragma unroll
  for (int mt = 0; mt < 4; ++mt)
    #pragma unroll
    for (int n0 = 0; n0 < 4; ++n0)
      #pragma unroll
      for (int r = 0; r < 4; ++r)
        Sb[(mt * 16 + quad * 4 + r) * 256 + wbase + n0 * 16 + li] =
            f2b(sa[mt][n0][r]);

  // ---- z final: sum wave partials, store ----------------------------------
  {
    int i2 = tid;
    float zz = zpart[0][i2] + zpart[1][i2] + zpart[2][i2] + zpart[3][i2];
    zloc[(size_t)blockIdx.x * 256 + i2] = zz;
  }
}

// ---- k_sprefix: in-place exclusive prefix of SlocT over chunks (bf16) ------
// short2-vectorized streaming in tiles of 16 (no VGPR spill).
__global__ __launch_bounds__(64) void k_sprefix(bf16* __restrict__ SlocT) {
  int b = blockIdx.x >> 7, g = blockIdx.x & 127;
  int p = g * 64 + threadIdx.x;                 // short2 column index [0,8192)
  unsigned* base = (unsigned*)(SlocT + (size_t)b * 2097152) + p;  // +8192/chunk
  float r0 = 0.f, r1 = 0.f;
  #pragma unroll 1
  for (int g16 = 0; g16 < 8; ++g16) {
    unsigned vb[16];
    #pragma unroll
    for (int j = 0; j < 16; ++j) vb[j] = base[(size_t)(g16 * 16 + j) * 8192];
    #pragma unroll
    for (int j = 0; j < 16; ++j) {
      unsigned u = vb[j];
      float t0 = bflo(u), t1 = bfhi(u);
      bf16 h0 = f2b(r0), h1 = f2b(r1);
      vb[j] = ((unsigned)*(unsigned short*)&h0) |
              (((unsigned)*(unsigned short*)&h1) << 16);
      r0 += t0; r1 += t1;
    }
    #pragma unroll
    for (int j = 0; j < 16; ++j) base[(size_t)(g16 * 16 + j) * 8192] = vb[j];
  }
}

// ---- k_zprefix: in-place exclusive prefix of zloc over chunks (f32) --------
__global__ __launch_bounds__(64) void k_zprefix(float* __restrict__ zloc) {
  int b = blockIdx.x >> 2, ig = blockIdx.x & 3;
  int i = ig * 64 + threadIdx.x;
  float* base = zloc + (size_t)b * 32768 + i;
  float run = 0.f;
  #pragma unroll 1
  for (int g16 = 0; g16 < 8; ++g16) {
    float vb[16];
    #pragma unroll
    for (int j = 0; j < 16; ++j) vb[j] = base[(size_t)(g16 * 16 + j) * 256];
    #pragma unroll
    for (int j = 0; j < 16; ++j) { float t = vb[j]; vb[j] = run; run += t; }
    #pragma unroll
    for (int j = 0; j < 16; ++j) base[(size_t)(g16 * 16 + j) * 256] = vb[j];
  }
}

// ---- k_out (MFMA): out[t] = (phiQ@Sp + tril(A)@V) / (phiQ.zp + rowsum + eps)
// 1024 blocks x 4 waves; wave w owns m-tile (rows m0=w*16 .. +15).
__global__ __launch_bounds__(256)
__attribute__((amdgpu_waves_per_eu(1, 2))) void k_out(
    const bf16* __restrict__ phiQ, const bf16* __restrict__ phiK,
    const void* __restrict__ v, const bf16* __restrict__ SlocT,
    const float* __restrict__ zloc, void* __restrict__ outp,
    const int* __restrict__ flag) {
  __shared__ short spT[64 * 264];   // SpT[d][i], pad 8     33792 B
  __shared__ short vTh[64 * 72];    // V^T hi bf16           9216 B
  __shared__ short vTl[64 * 72];    // V^T lo bf16           9216 B
  __shared__ short aT[64 * 72];     // masked A[t][tau]      9216 B

  int isf32 = *flag;
  int chunk = blockIdx.x;
  size_t tok0 = (size_t)chunk * 64;
  int tid = threadIdx.x;
  int lane = tid & 63;
  int li = lane & 15;
  int quad = lane >> 4;
  int w = __builtin_amdgcn_readfirstlane(tid >> 6);  // wave id = m-tile
  int m0 = w * 16;

  // ---- stage SpT: straight 16B copy of this chunk's exclusive-prefix S^T ---
  {
    const short* src = (const short*)SlocT + (size_t)chunk * 16384;
    #pragma unroll
    for (int it = 0; it < 8; ++it) {
      int e = it * 256 + tid;
      int d = e >> 5, seg = e & 31;
      *reinterpret_cast<short8*>(&spT[d * 264 + seg * 8]) =
          *reinterpret_cast<const short8*>(src + d * 256 + seg * 8);
    }
  }
  // ---- stage V^T split hi/lo (coalesced f32 reads; lo==0 for bf16 input) ---
  #pragma unroll
  for (int it = 0; it < 16; ++it) {
    int e = it * 256 + tid;
    int tau = e >> 6, d = e & 63;
    float vv = ldin(v, tok0 * 64 + e, isf32);
    bf16 h = f2b(vv);
    bf16 l = f2b(vv - b2f(h));
    vTh[d * 72 + tau] = *reinterpret_cast<short*>(&h);
    vTl[d * 72 + tau] = *reinterpret_cast<short*>(&l);
  }
  // ---- zero own above-diagonal A region (rows wave-private: no race) -------
  {
    shortx4 z4 = {0, 0, 0, 0};
    int arow = m0 + li;
    for (int cc = (w + 1) * 16 + quad * 4; cc < 64; cc += 16)
      *reinterpret_cast<shortx4*>(&aT[arow * 72 + cc]) = z4;
  }

  // ---- a1-frags: phiQ rows of this m-tile (L2-hot; reused mm1+mm2) ---------
  const short* pqf = (const short*)phiQ + (tok0 + m0 + li) * 256 + quad * 8;
  short8 a1[8];
  #pragma unroll
  for (int kk = 0; kk < 8; ++kk)
    a1[kk] = *reinterpret_cast<const short8*>(pqf + kk * 32);

  // ---- mm1: A tiles, n0 <= w only (tiles above diagonal are all-masked) ----
  floatx4 c1[4];
  #pragma unroll
  for (int n0 = 0; n0 < 4; ++n0) c1[n0] = (floatx4){0.f, 0.f, 0.f, 0.f};
  const short* pkb = (const short*)phiK + tok0 * 256;
  #pragma unroll
  for (int n0 = 0; n0 < 4; ++n0) {
    if (n0 <= w) {
      const short* bp = pkb + (size_t)(n0 * 16 + li) * 256 + quad * 8;
      floatx4 acc = c1[n0];
      #pragma unroll
      for (int kk = 0; kk < 8; ++kk) {
        short8 b = *reinterpret_cast<const short8*>(bp + kk * 32);
        acc = __builtin_amdgcn_mfma_f32_16x16x32_bf16(a1[kk], b, acc, 0, 0, 0);
      }
      c1[n0] = acc;
    }
  }

  // ---- tril mask + den rowsum partials + write bf16 A to own LDS rows ------
  float dpart[4] = {0.f, 0.f, 0.f, 0.f};
  #pragma unroll
  for (int n0 = 0; n0 < 4; ++n0) {
    if (n0 <= w) {
      int tau = n0 * 16 + li;
      #pragma unroll
      for (int r = 0; r < 4; ++r) {
        int t = m0 + quad * 4 + r;
        float val = (tau <= t) ? c1[n0][r] : 0.f;
        dpart[r] += val;
        bf16 hh = f2b(val);
        aT[t * 72 + tau] = *reinterpret_cast<short*>(&hh);
      }
    }
  }

  __syncthreads();   // spT/vTh/vTl ready (aT is wave-private: own rows only)

  // ---- mm2 (phiQ @ Sp) + mm3 (trilA @ Vhi + trilA @ Vlo), shared acc -------
  floatx4 o[4];
  #pragma unroll
  for (int n0 = 0; n0 < 4; ++n0) o[n0] = (floatx4){0.f, 0.f, 0.f, 0.f};

  const short* arow = &aT[(m0 + li) * 72 + quad * 8];
  short8 a3_0 = *reinterpret_cast<const short8*>(arow);
  short8 a3_1 = *reinterpret_cast<const short8*>(arow + 32);

  #pragma unroll
  for (int n0 = 0; n0 < 4; ++n0) {
    floatx4 acc = o[n0];
    const short* sp = &spT[(n0 * 16 + li) * 264 + quad * 8];
    #pragma unroll
    for (int kk = 0; kk < 8; ++kk) {
      short8 b = *reinterpret_cast<const short8*>(sp + kk * 32);
      acc = __builtin_amdgcn_mfma_f32_16x16x32_bf16(a1[kk], b, acc, 0, 0, 0);
    }
    const short* vph = &vTh[(n0 * 16 + li) * 72 + quad * 8];
    const short* vpl = &vTl[(n0 * 16 + li) * 72 + quad * 8];
    short8 bh0 = *reinterpret_cast<const short8*>(vph);
    short8 bh1 = *reinterpret_cast<const short8*>(vph + 32);
    short8 bl0 = *reinterpret_cast<const short8*>(vpl);
    short8 bl1 = *reinterpret_cast<const short8*>(vpl + 32);
    acc = __builtin_amdgcn_mfma_f32_16x16x32_bf16(a3_0, bh0, acc, 0, 0, 0);
    acc = __builtin_amdgcn_mfma_f32_16x16x32_bf16(a3_1, bh1, acc, 0, 0, 0);
    acc = __builtin_amdgcn_mfma_f32_16x16x32_bf16(a3_0, bl0, acc, 0, 0, 0);
    acc = __builtin_amdgcn_mfma_f32_16x16x32_bf16(a3_1, bl1, acc, 0, 0, 0);
    o[n0] = acc;
  }

  // ---- den: dpart += pq . zp  (lane li covers i in [li*16, li*16+16)) ------
  {
    const floatx4* zp4 =
        reinterpret_cast<const floatx4*>(zloc + (size_t)chunk * 256 + li * 16);
    floatx4 z0 = zp4[0], z1 = zp4[1], z2 = zp4[2], z3 = zp4[3];
    #pragma unroll
    for (int r = 0; r < 4; ++r) {
      const short* pqr =
          (const short*)phiQ + (tok0 + m0 + quad * 4 + r) * 256 + li * 16;
      short8 p0 = *reinterpret_cast<const short8*>(pqr);
      short8 p1 = *reinterpret_cast<const short8*>(pqr + 8);
      float s = dpart[r];
      #pragma unroll
      for (int j = 0; j < 4; ++j) s += bflo((unsigned short)p0[j]) * z0[j];
      #pragma unroll
      for (int j = 0; j < 4; ++j) s += bflo((unsigned short)p0[4 + j]) * z1[j];
      #pragma unroll
      for (int j = 0; j < 4; ++j) s += bflo((unsigned short)p1[j]) * z2[j];
      #pragma unroll
      for (int j = 0; j < 4; ++j) s += bflo((unsigned short)p1[4 + j]) * z3[j];
      dpart[r] = s;
    }
  }
  // butterfly over the quad's 16 lanes: every lane gets full den for its rows
  #pragma unroll
  for (int mask = 1; mask < 16; mask <<= 1) {
    #pragma unroll
    for (int r = 0; r < 4; ++r) dpart[r] += __shfl_xor(dpart[r], mask, 64);
  }

  // ---- epilogue: out[t][d] = (out1+out2) / (den + eps) ---------------------
  #pragma unroll
  for (int r = 0; r < 4; ++r) {
    float rd = 1.f / (dpart[r] + 1e-6f);
    size_t obb = (tok0 + m0 + quad * 4 + r) * 64 + li;
    if (isf32) {
      float* op = (float*)outp + obb;
      #pragma unroll
      for (int n0 = 0; n0 < 4; ++n0) op[n0 * 16] = o[n0][r] * rd;
    } else {
      bf16* op = (bf16*)outp + obb;
      #pragma unroll
      for (int n0 = 0; n0 < 4; ++n0) op[n0 * 16] = f2b(o[n0][r] * rd);
    }
  }
}

extern "C" void kernel_launch(void* const* d_in, const int* in_sizes, int n_in,
                              void* d_out, int out_size, void* d_ws, size_t ws_size,
                              hipStream_t stream) {
  (void)in_sizes; (void)n_in; (void)out_size;
  if (ws_size < NEED_WS_BYTES) return;   // diagnostic guard

  const void* q = d_in[0];
  const void* k = d_in[1];
  const void* v = d_in[2];
  const void* omega = d_in[3];

  int*   flag = (int*)d_ws;
  float* wsf  = (float*)d_ws + 64;       // data starts 256 B in
  bf16*  omb  = (bf16*)wsf;              // 16384 bf16
  float* zloc = wsf + 131072;            // 1024*256 f32
  bf16*  Sloc = (bf16*)(wsf + 393216);   // 1024*256*64 bf16 (TRANSPOSED [d][i])
  bf16*  phiQ = (bf16*)(wsf + 8781824);  // 65536*256 bf16
  bf16*  phiK = (bf16*)(wsf + 17170432); // 65536*256 bf16

  k_detect<<<1, 256, 0, stream>>>(q, flag);
  k_omega<<<64, 256, 0, stream>>>(omega, omb, flag);
  k_phiq<<<1024, 256, 0, stream>>>(q, omb, phiQ, flag);
  k_phik<<<1024, 256, 0, stream>>>(k, v, omb, phiK, Sloc, zloc, flag);
  k_sprefix<<<1024, 64, 0, stream>>>(Sloc);
  k_zprefix<<<32, 64, 0, stream>>>(zloc);
  k_out<<<1024, 256, 0, stream>>>(phiQ, phiK, v, Sloc, zloc, d_out, flag);
}

// Round 6
// 194.605 us; speedup vs baseline: 1.2067x; 1.0849x over previous
//
#include <hip/hip_runtime.h>
#include <hip/hip_bf16.h>

typedef __hip_bfloat16 bf16;
typedef __attribute__((ext_vector_type(8))) short short8;   // 8 bf16, 4 VGPRs
typedef __attribute__((ext_vector_type(4))) short shortx4;  // 4 bf16 (HIP owns "short4")
typedef __attribute__((ext_vector_type(4))) float floatx4;  // MFMA acc

// B=8, T=8192, D=64, M=256, chunk L=64, NCHUNK=1024, NTOK=65536
#define NEED_WS_BYTES 110625024ULL

__device__ __forceinline__ float b2f(bf16 x) { return __bfloat162float(x); }
__device__ __forceinline__ bf16  f2b(float x) { return __float2bfloat16(x); }
__device__ __forceinline__ float bflo(unsigned u) { return __uint_as_float(u << 16); }
__device__ __forceinline__ float bfhi(unsigned u) { return __uint_as_float(u & 0xffff0000u); }

// dtype-dispatched input load: isf32 ? f32 : bf16
__device__ __forceinline__ float ldin(const void* p, size_t i, int isf32) {
  return isf32 ? ((const float*)p)[i] : b2f(((const bf16*)p)[i]);
}

// f32 -> bf16 bits of (f * 0.125)
__device__ __forceinline__ short sb(float f) {
  bf16 h = f2b(f * 0.125f);
  return *reinterpret_cast<short*>(&h);
}
// bf16 bits -> bf16 bits of (x * 0.125) (exact exponent shift)
__device__ __forceinline__ short scale_b(short u) {
  float f = __uint_as_float(((unsigned)(unsigned short)u) << 16) * 0.125f;
  bf16 h = f2b(f);
  return *reinterpret_cast<short*>(&h);
}

// ---- k_detect: decide whether inputs are f32 or bf16 -----------------------
__global__ __launch_bounds__(256) void k_detect(const void* __restrict__ q,
                                                int* __restrict__ flag) {
  __shared__ int cnt;
  if (threadIdx.x == 0) cnt = 0;
  __syncthreads();
  const unsigned short* u = (const unsigned short*)q;
  int c = 0;
  for (int e = threadIdx.x; e < 2048; e += 256) {
    unsigned short w = u[2 * e];
    int ex = (w >> 7) & 0xFF;
    if ((w & 0x7FFF) != 0 && (ex < 110 || ex > 140)) c++;
  }
  atomicAdd(&cnt, c);
  __syncthreads();
  if (threadIdx.x == 0) *flag = (cnt > 512) ? 1 : 0;
}

// ---- k_omega: convert omega -> bf16 copy -----------------------------------
__global__ __launch_bounds__(256) void k_omega(const void* __restrict__ omega,
                                               bf16* __restrict__ omb,
                                               const int* __restrict__ flag) {
  int isf32 = *flag;
  int e = blockIdx.x * 256 + threadIdx.x;
  omb[e] = f2b(ldin(omega, e, isf32));
}

// ---- shared phi helpers ----------------------------------------------------
// Layouts (m89/m91-verified): A[m=lane&15][k=quad*8+j], B[n=lane&15][k=quad*8+j],
// C: col=lane&15 (n-dim), row=quad*4+reg (m-dim).
__device__ __forceinline__ void phi_load_a(const void* src, size_t row, int quad,
                                           int isf32, short8& a0, short8& a1) {
  if (isf32) {
    const float* xr = (const float*)src + row * 64;
    float4 f0 = *reinterpret_cast<const float4*>(xr + quad * 8);
    float4 f1 = *reinterpret_cast<const float4*>(xr + quad * 8 + 4);
    float4 f2 = *reinterpret_cast<const float4*>(xr + 32 + quad * 8);
    float4 f3 = *reinterpret_cast<const float4*>(xr + 32 + quad * 8 + 4);
    a0[0] = sb(f0.x); a0[1] = sb(f0.y); a0[2] = sb(f0.z); a0[3] = sb(f0.w);
    a0[4] = sb(f1.x); a0[5] = sb(f1.y); a0[6] = sb(f1.z); a0[7] = sb(f1.w);
    a1[0] = sb(f2.x); a1[1] = sb(f2.y); a1[2] = sb(f2.z); a1[3] = sb(f2.w);
    a1[4] = sb(f3.x); a1[5] = sb(f3.y); a1[6] = sb(f3.z); a1[7] = sb(f3.w);
  } else {
    const short* xr = (const short*)src + row * 64;
    short8 r0 = *reinterpret_cast<const short8*>(xr + quad * 8);
    short8 r1 = *reinterpret_cast<const short8*>(xr + 32 + quad * 8);
    #pragma unroll
    for (int j = 0; j < 8; ++j) { a0[j] = scale_b(r0[j]); a1[j] = scale_b(r1[j]); }
  }
}

__device__ __forceinline__ void phi_mfma(const bf16* omb, int li, int quad,
                                         const short8& a0, const short8& a1,
                                         floatx4* c, float* mx) {
  #pragma unroll
  for (int n0 = 0; n0 < 16; ++n0) {
    const short* bp = (const short*)omb + (size_t)(n0 * 16 + li) * 64 + quad * 8;
    short8 b0 = *reinterpret_cast<const short8*>(bp);
    short8 b1 = *reinterpret_cast<const short8*>(bp + 32);
    floatx4 acc = {0.f, 0.f, 0.f, 0.f};
    acc = __builtin_amdgcn_mfma_f32_16x16x32_bf16(a0, b0, acc, 0, 0, 0);
    acc = __builtin_amdgcn_mfma_f32_16x16x32_bf16(a1, b1, acc, 0, 0, 0);
    c[n0] = acc;
  }
  #pragma unroll
  for (int r = 0; r < 4; ++r) {
    float m = c[0][r];
    #pragma unroll
    for (int n0 = 1; n0 < 16; ++n0) m = fmaxf(m, c[n0][r]);
    mx[r] = m;
  }
  #pragma unroll
  for (int mask = 1; mask < 16; mask <<= 1) {
    #pragma unroll
    for (int r = 0; r < 4; ++r) mx[r] = fmaxf(mx[r], __shfl_xor(mx[r], mask, 64));
  }
}

// ---- k_phik: phiK + fused S^T/z (unchanged from R5) ------------------------
__global__ __launch_bounds__(256)
__attribute__((amdgpu_waves_per_eu(1, 2))) void k_phik(
    const void* __restrict__ k, const void* __restrict__ v,
    const bf16* __restrict__ omb, bf16* __restrict__ phiK,
    bf16* __restrict__ SlocT, float* __restrict__ zloc,
    const int* __restrict__ flag) {
  __shared__ short ob[4][16][136];   // 17408 B  per-wave store tile
  __shared__ short pkT[256 * 72];    // 36864 B  phiK^T [i][t]
  __shared__ short vTh[64 * 72];     //  9216 B  V^T hi
  __shared__ short vTl[64 * 72];     //  9216 B  V^T lo
  __shared__ float zpart[4][256];    //  4096 B  per-wave z partials

  int isf32 = *flag;
  int tid = threadIdx.x;
  size_t tok0 = (size_t)blockIdx.x * 64;
  int li = tid & 15;
  int quad = (tid >> 4) & 3;
  int w = tid >> 6;
  int m0 = w * 16;
  size_t row = tok0 + m0 + li;

  // ---- stage V^T hi/lo -----------------------------------------------------
  #pragma unroll
  for (int it = 0; it < 16; ++it) {
    int e = it * 256 + tid;
    int tau = e >> 6, d = e & 63;
    float vv = ldin(v, tok0 * 64 + e, isf32);
    bf16 h = f2b(vv);
    bf16 l = f2b(vv - b2f(h));
    vTh[d * 72 + tau] = *reinterpret_cast<short*>(&h);
    vTl[d * 72 + tau] = *reinterpret_cast<short*>(&l);
  }

  // ---- phi compute ---------------------------------------------------------
  short8 a0, a1;
  phi_load_a(k, row, quad, isf32, a0, a1);
  floatx4 c[16];
  float mx[4];
  phi_mfma(omb, li, quad, a0, a1, c, mx);

  // ---- exp -> ob (coalesced global store) + pkT (transposed) + z partials --
  float zl[16];
  #pragma unroll
  for (int f = 0; f < 16; ++f) zl[f] = 0.f;
  size_t srow = tok0 + m0 + li;
  #pragma unroll
  for (int h = 0; h < 2; ++h) {
    #pragma unroll
    for (int r = 0; r < 4; ++r) {
      #pragma unroll
      for (int n = 0; n < 8; ++n) {
        bf16 hv = f2b(__expf(c[h * 8 + n][r] - mx[r]) * 0.0625f);  // 1/sqrt(256)
        short hb = *reinterpret_cast<short*>(&hv);
        ob[w][quad * 4 + r][n * 16 + li] = hb;
        pkT[((h * 8 + n) * 16 + li) * 72 + (m0 + quad * 4 + r)] = hb;
        zl[h * 8 + n] += bflo((unsigned)(unsigned short)hb);  // rounded value
      }
    }
    #pragma unroll
    for (int it = 0; it < 4; ++it) {
      int ch = it * 4 + quad;
      short8 vv = *reinterpret_cast<const short8*>(&ob[w][li][ch * 8]);
      *reinterpret_cast<short8*>((short*)phiK + srow * 256 + h * 128 + ch * 8) = vv;
    }
  }
  // z: reduce each feature over this wave's 16 tokens (4 quads x 4 r)
  #pragma unroll
  for (int f = 0; f < 16; ++f) {
    float vz = zl[f];
    vz += __shfl_xor(vz, 16, 64);
    vz += __shfl_xor(vz, 32, 64);
    if (quad == 0) zpart[w][f * 16 + li] = vz;
  }

  __syncthreads();   // pkT, vTh/vTl, zpart ready

  // ---- S GEMM: wave w -> features [w*64, w*64+64), all d ------------------
  int wbase = w * 64;
  floatx4 sa[4][4];
  #pragma unroll
  for (int mt = 0; mt < 4; ++mt)
    #pragma unroll
    for (int n0 = 0; n0 < 4; ++n0) sa[mt][n0] = (floatx4){0.f, 0.f, 0.f, 0.f};

  #pragma unroll
  for (int h = 0; h < 2; ++h) {
    short8 Ah[4], Al[4];
    #pragma unroll
    for (int mt = 0; mt < 4; ++mt) {
      Ah[mt] = *reinterpret_cast<const short8*>(
          &vTh[(mt * 16 + li) * 72 + h * 32 + quad * 8]);
      Al[mt] = *reinterpret_cast<const short8*>(
          &vTl[(mt * 16 + li) * 72 + h * 32 + quad * 8]);
    }
    #pragma unroll
    for (int n0 = 0; n0 < 4; ++n0) {
      short8 Bq = *reinterpret_cast<const short8*>(
          &pkT[(wbase + n0 * 16 + li) * 72 + h * 32 + quad * 8]);
      #pragma unroll
      for (int mt = 0; mt < 4; ++mt) {
        sa[mt][n0] =
            __builtin_amdgcn_mfma_f32_16x16x32_bf16(Ah[mt], Bq, sa[mt][n0], 0, 0, 0);
        sa[mt][n0] =
            __builtin_amdgcn_mfma_f32_16x16x32_bf16(Al[mt], Bq, sa[mt][n0], 0, 0, 0);
      }
    }
  }

  // ---- store S^T (bf16) ----------------------------------------------------
  bf16* Sb = SlocT + (size_t)blockIdx.x * 16384;
  #pragma unroll
  for (int mt = 0; mt < 4; ++mt)
    #pragma unroll
    for (int n0 = 0; n0 < 4; ++n0)
      #pragma unroll
      for (int r = 0; r < 4; ++r)
        Sb[(mt * 16 + quad * 4 + r) * 256 + wbase + n0 * 16 + li] =
            f2b(sa[mt][n0][r]);

  // ---- z final: sum wave partials, store ----------------------------------
  {
    int i2 = tid;
    float zz = zpart[0][i2] + zpart[1][i2] + zpart[2][i2] + zpart[3][i2];
    zloc[(size_t)blockIdx.x * 256 + i2] = zz;
  }
}

// ---- k_sprefix: in-place exclusive prefix of SlocT over chunks (bf16) ------
__global__ __launch_bounds__(64) void k_sprefix(bf16* __restrict__ SlocT) {
  int b = blockIdx.x >> 7, g = blockIdx.x & 127;
  int p = g * 64 + threadIdx.x;                 // short2 column index [0,8192)
  unsigned* base = (unsigned*)(SlocT + (size_t)b * 2097152) + p;  // +8192/chunk
  float r0 = 0.f, r1 = 0.f;
  #pragma unroll 1
  for (int g16 = 0; g16 < 8; ++g16) {
    unsigned vb[16];
    #pragma unroll
    for (int j = 0; j < 16; ++j) vb[j] = base[(size_t)(g16 * 16 + j) * 8192];
    #pragma unroll
    for (int j = 0; j < 16; ++j) {
      unsigned u = vb[j];
      float t0 = bflo(u), t1 = bfhi(u);
      bf16 h0 = f2b(r0), h1 = f2b(r1);
      vb[j] = ((unsigned)*(unsigned short*)&h0) |
              (((unsigned)*(unsigned short*)&h1) << 16);
      r0 += t0; r1 += t1;
    }
    #pragma unroll
    for (int j = 0; j < 16; ++j) base[(size_t)(g16 * 16 + j) * 8192] = vb[j];
  }
}

// ---- k_zprefix: in-place exclusive prefix of zloc over chunks (f32) --------
__global__ __launch_bounds__(64) void k_zprefix(float* __restrict__ zloc) {
  int b = blockIdx.x >> 2, ig = blockIdx.x & 3;
  int i = ig * 64 + threadIdx.x;
  float* base = zloc + (size_t)b * 32768 + i;
  float run = 0.f;
  #pragma unroll 1
  for (int g16 = 0; g16 < 8; ++g16) {
    float vb[16];
    #pragma unroll
    for (int j = 0; j < 16; ++j) vb[j] = base[(size_t)(g16 * 16 + j) * 256];
    #pragma unroll
    for (int j = 0; j < 16; ++j) { float t = vb[j]; vb[j] = run; run += t; }
    #pragma unroll
    for (int j = 0; j < 16; ++j) base[(size_t)(g16 * 16 + j) * 256] = vb[j];
  }
}

// ---- k_out (R6: phiQ computed IN-KERNEL; k_phiq + phiQ global buffer gone) -
// out[t] = (phiQ@Sp + tril(A)@V) / (phiQ.zp + rowsum(tril A) + eps)
// Phase 1: phiQ = exp(q/8 @ omb^T - rowmax)/16 via MFMA, rounded bf16 bits ->
//          spT LDS (dual-use buffer) + den partials (pq.zp) from same bits.
//          Wave w writes/reads ONLY rows m0..m0+15 -> no barrier needed
//          between pqs write and a1-frag read (within-wave lgkmcnt ordering).
// Barrier 1 (all waves done reading pqs) -> re-stage spT with Sp.
// mm1: A = phiQ @ phiK^T (K=256, triangular n0<=w), masked, rowsum, aT LDS.
// Barrier 2 -> mm2 (phiQ @ Sp) + mm3 (trilA @ V hi/lo), den butterfly, store.
// LDS unchanged 61440 B -> 2 blocks/CU; waves_per_eu(1,2).
__global__ __launch_bounds__(256)
__attribute__((amdgpu_waves_per_eu(1, 2))) void k_out(
    const void* __restrict__ q, const bf16* __restrict__ omb,
    const bf16* __restrict__ phiK, const void* __restrict__ v,
    const bf16* __restrict__ SlocT, const float* __restrict__ zloc,
    void* __restrict__ outp, const int* __restrict__ flag) {
  __shared__ short spT[64 * 264];   // phase A: pqs phiQ[t][i]; phase B: SpT[d][i]
  __shared__ short vTh[64 * 72];    // V^T hi bf16           9216 B
  __shared__ short vTl[64 * 72];    // V^T lo bf16           9216 B
  __shared__ short aT[64 * 72];     // masked A[t][tau]      9216 B

  int isf32 = *flag;
  int chunk = blockIdx.x;
  size_t tok0 = (size_t)chunk * 64;
  int tid = threadIdx.x;
  int lane = tid & 63;
  int li = lane & 15;
  int quad = lane >> 4;
  int w = __builtin_amdgcn_readfirstlane(tid >> 6);  // wave id = m-tile
  int m0 = w * 16;

  // ---- stage V^T split hi/lo (latency hidden under phase 1 compute) -------
  #pragma unroll
  for (int it = 0; it < 16; ++it) {
    int e = it * 256 + tid;
    int tau = e >> 6, d = e & 63;
    float vv = ldin(v, tok0 * 64 + e, isf32);
    bf16 h = f2b(vv);
    bf16 l = f2b(vv - b2f(h));
    vTh[d * 72 + tau] = *reinterpret_cast<short*>(&h);
    vTl[d * 72 + tau] = *reinterpret_cast<short*>(&l);
  }
  // ---- zero own above-diagonal A region (rows wave-private) ----------------
  {
    shortx4 z4 = {0, 0, 0, 0};
    int arow0 = m0 + li;
    for (int cc = (w + 1) * 16 + quad * 4; cc < 64; cc += 16)
      *reinterpret_cast<shortx4*>(&aT[arow0 * 72 + cc]) = z4;
  }

  // ---- phase 1: phiQ in-kernel ---------------------------------------------
  float dpart[4] = {0.f, 0.f, 0.f, 0.f};
  {
    short8 qa0, qa1;
    phi_load_a(q, tok0 + m0 + li, quad, isf32, qa0, qa1);
    floatx4 c[16];
    float mx[4];
    phi_mfma(omb, li, quad, qa0, qa1, c, mx);

    const float* zp = zloc + (size_t)chunk * 256;
    #pragma unroll
    for (int n0 = 0; n0 < 16; ++n0) {
      float zv = zp[n0 * 16 + li];
      #pragma unroll
      for (int r = 0; r < 4; ++r) {
        bf16 hv = f2b(__expf(c[n0][r] - mx[r]) * 0.0625f);  // 1/sqrt(256)
        short hb = *reinterpret_cast<short*>(&hv);
        spT[(m0 + quad * 4 + r) * 264 + n0 * 16 + li] = hb;  // own rows only
        dpart[r] += bflo((unsigned)(unsigned short)hb) * zv; // rounded bits
      }
    }
  }

  // ---- a1-frags from own pqs rows (no barrier: wave-private) ---------------
  const short* pqf = &spT[(m0 + li) * 264 + quad * 8];
  short8 a1[8];
  #pragma unroll
  for (int kk = 0; kk < 8; ++kk)
    a1[kk] = *reinterpret_cast<const short8*>(pqf + kk * 32);

  __syncthreads();   // all waves done reading pqs -> safe to overwrite spT

  // ---- re-stage spT with Sp (16B copies; latency hides under mm1) ----------
  {
    const short* src = (const short*)SlocT + (size_t)chunk * 16384;
    #pragma unroll
    for (int it = 0; it < 8; ++it) {
      int e = it * 256 + tid;
      int d = e >> 5, seg = e & 31;
      *reinterpret_cast<short8*>(&spT[d * 264 + seg * 8]) =
          *reinterpret_cast<const short8*>(src + d * 256 + seg * 8);
    }
  }

  // ---- mm1: A tiles, n0 <= w only ------------------------------------------
  floatx4 c1[4];
  #pragma unroll
  for (int n0 = 0; n0 < 4; ++n0) c1[n0] = (floatx4){0.f, 0.f, 0.f, 0.f};
  const short* pkb = (const short*)phiK + tok0 * 256;
  #pragma unroll
  for (int n0 = 0; n0 < 4; ++n0) {
    if (n0 <= w) {
      const short* bp = pkb + (size_t)(n0 * 16 + li) * 256 + quad * 8;
      floatx4 acc = c1[n0];
      #pragma unroll
      for (int kk = 0; kk < 8; ++kk) {
        short8 b = *reinterpret_cast<const short8*>(bp + kk * 32);
        acc = __builtin_amdgcn_mfma_f32_16x16x32_bf16(a1[kk], b, acc, 0, 0, 0);
      }
      c1[n0] = acc;
    }
  }

  // ---- tril mask + den rowsum partials + write bf16 A to own LDS rows ------
  #pragma unroll
  for (int n0 = 0; n0 < 4; ++n0) {
    if (n0 <= w) {
      int tau = n0 * 16 + li;
      #pragma unroll
      for (int r = 0; r < 4; ++r) {
        int t = m0 + quad * 4 + r;
        float val = (tau <= t) ? c1[n0][r] : 0.f;
        dpart[r] += val;
        bf16 hh = f2b(val);
        aT[t * 72 + tau] = *reinterpret_cast<short*>(&hh);
      }
    }
  }

  __syncthreads();   // SpT staged, vT ready (aT is wave-private)

  // ---- mm2 (phiQ @ Sp) + mm3 (trilA @ Vhi + trilA @ Vlo), shared acc -------
  floatx4 o[4];
  #pragma unroll
  for (int n0 = 0; n0 < 4; ++n0) o[n0] = (floatx4){0.f, 0.f, 0.f, 0.f};

  const short* arow = &aT[(m0 + li) * 72 + quad * 8];
  short8 a3_0 = *reinterpret_cast<const short8*>(arow);
  short8 a3_1 = *reinterpret_cast<const short8*>(arow + 32);

  #pragma unroll
  for (int n0 = 0; n0 < 4; ++n0) {
    floatx4 acc = o[n0];
    const short* sp = &spT[(n0 * 16 + li) * 264 + quad * 8];
    #pragma unroll
    for (int kk = 0; kk < 8; ++kk) {
      short8 b = *reinterpret_cast<const short8*>(sp + kk * 32);
      acc = __builtin_amdgcn_mfma_f32_16x16x32_bf16(a1[kk], b, acc, 0, 0, 0);
    }
    const short* vph = &vTh[(n0 * 16 + li) * 72 + quad * 8];
    const short* vpl = &vTl[(n0 * 16 + li) * 72 + quad * 8];
    short8 bh0 = *reinterpret_cast<const short8*>(vph);
    short8 bh1 = *reinterpret_cast<const short8*>(vph + 32);
    short8 bl0 = *reinterpret_cast<const short8*>(vpl);
    short8 bl1 = *reinterpret_cast<const short8*>(vpl + 32);
    acc = __builtin_amdgcn_mfma_f32_16x16x32_bf16(a3_0, bh0, acc, 0, 0, 0);
    acc = __builtin_amdgcn_mfma_f32_16x16x32_bf16(a3_1, bh1, acc, 0, 0, 0);
    acc = __builtin_amdgcn_mfma_f32_16x16x32_bf16(a3_0, bl0, acc, 0, 0, 0);
    acc = __builtin_amdgcn_mfma_f32_16x16x32_bf16(a3_1, bl1, acc, 0, 0, 0);
    o[n0] = acc;
  }

  // butterfly over the quad's 16 lanes: every lane gets full den for its rows
  #pragma unroll
  for (int mask = 1; mask < 16; mask <<= 1) {
    #pragma unroll
    for (int r = 0; r < 4; ++r) dpart[r] += __shfl_xor(dpart[r], mask, 64);
  }

  // ---- epilogue: out[t][d] = (out1+out2) / (den + eps) ---------------------
  #pragma unroll
  for (int r = 0; r < 4; ++r) {
    float rd = 1.f / (dpart[r] + 1e-6f);
    size_t obb = (tok0 + m0 + quad * 4 + r) * 64 + li;
    if (isf32) {
      float* op = (float*)outp + obb;
      #pragma unroll
      for (int n0 = 0; n0 < 4; ++n0) op[n0 * 16] = o[n0][r] * rd;
    } else {
      bf16* op = (bf16*)outp + obb;
      #pragma unroll
      for (int n0 = 0; n0 < 4; ++n0) op[n0 * 16] = f2b(o[n0][r] * rd);
    }
  }
}

extern "C" void kernel_launch(void* const* d_in, const int* in_sizes, int n_in,
                              void* d_out, int out_size, void* d_ws, size_t ws_size,
                              hipStream_t stream) {
  (void)in_sizes; (void)n_in; (void)out_size;
  if (ws_size < NEED_WS_BYTES) return;   // diagnostic guard

  const void* q = d_in[0];
  const void* k = d_in[1];
  const void* v = d_in[2];
  const void* omega = d_in[3];

  int*   flag = (int*)d_ws;
  float* wsf  = (float*)d_ws + 64;       // data starts 256 B in
  bf16*  omb  = (bf16*)wsf;              // 16384 bf16
  float* zloc = wsf + 131072;            // 1024*256 f32
  bf16*  Sloc = (bf16*)(wsf + 393216);   // 1024*256*64 bf16 (TRANSPOSED [d][i])
  bf16*  phiK = (bf16*)(wsf + 17170432); // 65536*256 bf16
  // phiQ region (wsf + 8781824) no longer used: phiQ lives in-kernel (R6).

  k_detect<<<1, 256, 0, stream>>>(q, flag);
  k_omega<<<64, 256, 0, stream>>>(omega, omb, flag);
  k_phik<<<1024, 256, 0, stream>>>(k, v, omb, phiK, Sloc, zloc, flag);
  k_sprefix<<<1024, 64, 0, stream>>>(Sloc);
  k_zprefix<<<32, 64, 0, stream>>>(zloc);
  k_out<<<1024, 256, 0, stream>>>(q, omb, phiK, v, Sloc, zloc, d_out, flag);
}

// Round 7
// 190.931 us; speedup vs baseline: 1.2299x; 1.0192x over previous
//
#include <hip/hip_runtime.h>
#include <hip/hip_bf16.h>

typedef __hip_bfloat16 bf16;
typedef __attribute__((ext_vector_type(8))) short short8;   // 8 bf16, 4 VGPRs
typedef __attribute__((ext_vector_type(4))) short shortx4;  // 4 bf16 (HIP owns "short4")
typedef __attribute__((ext_vector_type(4))) float floatx4;  // MFMA acc

// B=8, T=8192, D=64, M=256, chunk L=64, NCHUNK=1024, NTOK=65536
#define NEED_WS_BYTES 110625024ULL

__device__ __forceinline__ float b2f(bf16 x) { return __bfloat162float(x); }
__device__ __forceinline__ bf16  f2b(float x) { return __float2bfloat16(x); }
__device__ __forceinline__ float bflo(unsigned u) { return __uint_as_float(u << 16); }
__device__ __forceinline__ float bfhi(unsigned u) { return __uint_as_float(u & 0xffff0000u); }

// dtype-dispatched input load: isf32 ? f32 : bf16
__device__ __forceinline__ float ldin(const void* p, size_t i, int isf32) {
  return isf32 ? ((const float*)p)[i] : b2f(((const bf16*)p)[i]);
}

// f32 -> bf16 bits of (f * 0.125)
__device__ __forceinline__ short sb(float f) {
  bf16 h = f2b(f * 0.125f);
  return *reinterpret_cast<short*>(&h);
}
// bf16 bits -> bf16 bits of (x * 0.125) (exact exponent shift)
__device__ __forceinline__ short scale_b(short u) {
  float f = __uint_as_float(((unsigned)(unsigned short)u) << 16) * 0.125f;
  bf16 h = f2b(f);
  return *reinterpret_cast<short*>(&h);
}

// ---- k_detect: decide whether inputs are f32 or bf16 -----------------------
__global__ __launch_bounds__(256) void k_detect(const void* __restrict__ q,
                                                int* __restrict__ flag) {
  __shared__ int cnt;
  if (threadIdx.x == 0) cnt = 0;
  __syncthreads();
  const unsigned short* u = (const unsigned short*)q;
  int c = 0;
  for (int e = threadIdx.x; e < 2048; e += 256) {
    unsigned short w = u[2 * e];
    int ex = (w >> 7) & 0xFF;
    if ((w & 0x7FFF) != 0 && (ex < 110 || ex > 140)) c++;
  }
  atomicAdd(&cnt, c);
  __syncthreads();
  if (threadIdx.x == 0) *flag = (cnt > 512) ? 1 : 0;
}

// ---- k_omega: convert omega -> bf16 copy -----------------------------------
__global__ __launch_bounds__(256) void k_omega(const void* __restrict__ omega,
                                               bf16* __restrict__ omb,
                                               const int* __restrict__ flag) {
  int isf32 = *flag;
  int e = blockIdx.x * 256 + threadIdx.x;
  omb[e] = f2b(ldin(omega, e, isf32));
}

// ---- shared phi helpers ----------------------------------------------------
// Layouts (m89/m91-verified): A[m=lane&15][k=quad*8+j], B[n=lane&15][k=quad*8+j],
// C: col=lane&15 (n-dim), row=quad*4+reg (m-dim).
__device__ __forceinline__ void phi_load_a(const void* src, size_t row, int quad,
                                           int isf32, short8& a0, short8& a1) {
  if (isf32) {
    const float* xr = (const float*)src + row * 64;
    float4 f0 = *reinterpret_cast<const float4*>(xr + quad * 8);
    float4 f1 = *reinterpret_cast<const float4*>(xr + quad * 8 + 4);
    float4 f2 = *reinterpret_cast<const float4*>(xr + 32 + quad * 8);
    float4 f3 = *reinterpret_cast<const float4*>(xr + 32 + quad * 8 + 4);
    a0[0] = sb(f0.x); a0[1] = sb(f0.y); a0[2] = sb(f0.z); a0[3] = sb(f0.w);
    a0[4] = sb(f1.x); a0[5] = sb(f1.y); a0[6] = sb(f1.z); a0[7] = sb(f1.w);
    a1[0] = sb(f2.x); a1[1] = sb(f2.y); a1[2] = sb(f2.z); a1[3] = sb(f2.w);
    a1[4] = sb(f3.x); a1[5] = sb(f3.y); a1[6] = sb(f3.z); a1[7] = sb(f3.w);
  } else {
    const short* xr = (const short*)src + row * 64;
    short8 r0 = *reinterpret_cast<const short8*>(xr + quad * 8);
    short8 r1 = *reinterpret_cast<const short8*>(xr + 32 + quad * 8);
    #pragma unroll
    for (int j = 0; j < 8; ++j) { a0[j] = scale_b(r0[j]); a1[j] = scale_b(r1[j]); }
  }
}

__device__ __forceinline__ void phi_mfma(const bf16* omb, int li, int quad,
                                         const short8& a0, const short8& a1,
                                         floatx4* c, float* mx) {
  #pragma unroll
  for (int n0 = 0; n0 < 16; ++n0) {
    const short* bp = (const short*)omb + (size_t)(n0 * 16 + li) * 64 + quad * 8;
    short8 b0 = *reinterpret_cast<const short8*>(bp);
    short8 b1 = *reinterpret_cast<const short8*>(bp + 32);
    floatx4 acc = {0.f, 0.f, 0.f, 0.f};
    acc = __builtin_amdgcn_mfma_f32_16x16x32_bf16(a0, b0, acc, 0, 0, 0);
    acc = __builtin_amdgcn_mfma_f32_16x16x32_bf16(a1, b1, acc, 0, 0, 0);
    c[n0] = acc;
  }
  #pragma unroll
  for (int r = 0; r < 4; ++r) {
    float m = c[0][r];
    #pragma unroll
    for (int n0 = 1; n0 < 16; ++n0) m = fmaxf(m, c[n0][r]);
    mx[r] = m;
  }
  #pragma unroll
  for (int mask = 1; mask < 16; mask <<= 1) {
    #pragma unroll
    for (int r = 0; r < 4; ++r) mx[r] = fmaxf(mx[r], __shfl_xor(mx[r], mask, 64));
  }
}

// ---- k_phik (R7): phiK + fused S^T/z, LDS 76.8K -> 51.2K = 3 blocks/CU -----
// Changes vs R5/R6: (a) ob dropped -> phiK stored via direct 2B scatter
// (4x32B segments/instr; fire-and-forget); (b) zpart dropped -> z[i] = rowsum
// of pkT row i after the barrier (same rounded bf16 values, f32 reassoc);
// (c) pkT 256x72 -> 256x64 with XOR chunk swizzle c' = c ^ (i&7): read b128
// stays ~2-way (free), 16B alignment kept; (d) waves_per_eu(1,3) for the
// 12 waves/CU that 3 blocks allow (88 VGPR <= 170, no demotion risk).
// Tripwire: FETCH balloon = spill = revert.
__global__ __launch_bounds__(256)
__attribute__((amdgpu_waves_per_eu(1, 3))) void k_phik(
    const void* __restrict__ k, const void* __restrict__ v,
    const bf16* __restrict__ omb, bf16* __restrict__ phiK,
    bf16* __restrict__ SlocT, float* __restrict__ zloc,
    const int* __restrict__ flag) {
  __shared__ short pkT[256 * 64];    // 32768 B  phiK^T [i][t], chunk-swizzled
  __shared__ short vTh[64 * 72];     //  9216 B  V^T hi
  __shared__ short vTl[64 * 72];     //  9216 B  V^T lo

  int isf32 = *flag;
  int tid = threadIdx.x;
  size_t tok0 = (size_t)blockIdx.x * 64;
  int li = tid & 15;
  int quad = (tid >> 4) & 3;
  int w = tid >> 6;
  int m0 = w * 16;
  size_t row = tok0 + m0 + li;

  // ---- stage V^T hi/lo -----------------------------------------------------
  #pragma unroll
  for (int it = 0; it < 16; ++it) {
    int e = it * 256 + tid;
    int tau = e >> 6, d = e & 63;
    float vv = ldin(v, tok0 * 64 + e, isf32);
    bf16 h = f2b(vv);
    bf16 l = f2b(vv - b2f(h));
    vTh[d * 72 + tau] = *reinterpret_cast<short*>(&h);
    vTl[d * 72 + tau] = *reinterpret_cast<short*>(&l);
  }

  // ---- phi compute ---------------------------------------------------------
  short8 a0, a1;
  phi_load_a(k, row, quad, isf32, a0, a1);
  floatx4 c[16];
  float mx[4];
  phi_mfma(omb, li, quad, a0, a1, c, mx);

  // ---- exp -> phiK global scatter + swizzled pkT ---------------------------
  #pragma unroll
  for (int n0 = 0; n0 < 16; ++n0) {
    #pragma unroll
    for (int r = 0; r < 4; ++r) {
      bf16 hv = f2b(__expf(c[n0][r] - mx[r]) * 0.0625f);  // 1/sqrt(256)
      short hb = *reinterpret_cast<short*>(&hv);
      int i = n0 * 16 + li;
      int t = m0 + quad * 4 + r;
      ((short*)phiK)[(tok0 + t) * 256 + i] = hb;            // 4x32B segs/instr
      int cch = (t >> 3) ^ (i & 7);                         // XOR chunk swizzle
      pkT[i * 64 + cch * 8 + (t & 7)] = hb;
    }
  }

  __syncthreads();   // pkT, vTh/vTl ready

  // ---- z[i] = rowsum of pkT row i (same rounded values as stored) ----------
  {
    int i2 = tid;
    float zz = 0.f;
    #pragma unroll
    for (int c8 = 0; c8 < 8; ++c8) {
      short8 vv8 = *reinterpret_cast<const short8*>(
          &pkT[i2 * 64 + (c8 ^ (i2 & 7)) * 8]);
      #pragma unroll
      for (int j = 0; j < 8; ++j) zz += bflo((unsigned)(unsigned short)vv8[j]);
    }
    zloc[(size_t)blockIdx.x * 256 + i2] = zz;
  }

  // ---- S GEMM: wave w -> features [w*64, w*64+64), all d ------------------
  int wbase = w * 64;
  floatx4 sa[4][4];
  #pragma unroll
  for (int mt = 0; mt < 4; ++mt)
    #pragma unroll
    for (int n0 = 0; n0 < 4; ++n0) sa[mt][n0] = (floatx4){0.f, 0.f, 0.f, 0.f};

  #pragma unroll
  for (int h = 0; h < 2; ++h) {
    short8 Ah[4], Al[4];
    #pragma unroll
    for (int mt = 0; mt < 4; ++mt) {
      Ah[mt] = *reinterpret_cast<const short8*>(
          &vTh[(mt * 16 + li) * 72 + h * 32 + quad * 8]);
      Al[mt] = *reinterpret_cast<const short8*>(
          &vTl[(mt * 16 + li) * 72 + h * 32 + quad * 8]);
    }
    #pragma unroll
    for (int n0 = 0; n0 < 4; ++n0) {
      int crow = wbase + n0 * 16 + li;
      int cc = (h * 4 + quad) ^ (li & 7);
      short8 Bq = *reinterpret_cast<const short8*>(&pkT[crow * 64 + cc * 8]);
      #pragma unroll
      for (int mt = 0; mt < 4; ++mt) {
        sa[mt][n0] =
            __builtin_amdgcn_mfma_f32_16x16x32_bf16(Ah[mt], Bq, sa[mt][n0], 0, 0, 0);
        sa[mt][n0] =
            __builtin_amdgcn_mfma_f32_16x16x32_bf16(Al[mt], Bq, sa[mt][n0], 0, 0, 0);
      }
    }
  }

  // ---- store S^T (bf16) ----------------------------------------------------
  bf16* Sb = SlocT + (size_t)blockIdx.x * 16384;
  #pragma unroll
  for (int mt = 0; mt < 4; ++mt)
    #pragma unroll
    for (int n0 = 0; n0 < 4; ++n0)
      #pragma unroll
      for (int r = 0; r < 4; ++r)
        Sb[(mt * 16 + quad * 4 + r) * 256 + wbase + n0 * 16 + li] =
            f2b(sa[mt][n0][r]);
}

// ---- k_prefix (R7): merged hierarchical exclusive scans --------------------
// Blocks [0,1024): S-scan. 4 waves/block; wave w scans chunks [w*32,w*32+32)
// of 64 short2-columns (all 32 loads in flight), cross-wave offset via LDS
// totals + 1 barrier, then register re-scan applies offset. Serial chain
// 128 -> 32 steps, 4224 waves (16/CU) vs 1024 (4/CU).
// Blocks [1024,1056): z-scan, same scheme in f32.
__global__ __launch_bounds__(256) void k_prefix(bf16* __restrict__ SlocT,
                                                float* __restrict__ zloc) {
  __shared__ float tot[4][64][2];
  int tid = threadIdx.x;
  int lane = tid & 63;
  int w = tid >> 6;
  if (blockIdx.x < 1024) {
    int b = blockIdx.x >> 7, g = blockIdx.x & 127;
    int p = g * 64 + lane;                    // short2 column [0,8192)
    unsigned* base = (unsigned*)(SlocT + (size_t)b * 2097152) + p;
    unsigned vb[32];
    #pragma unroll
    for (int j = 0; j < 32; ++j) vb[j] = base[(size_t)(w * 32 + j) * 8192];
    float t0 = 0.f, t1 = 0.f;
    #pragma unroll
    for (int j = 0; j < 32; ++j) { t0 += bflo(vb[j]); t1 += bfhi(vb[j]); }
    tot[w][lane][0] = t0; tot[w][lane][1] = t1;
    __syncthreads();
    float r0 = 0.f, r1 = 0.f;
    for (int w2 = 0; w2 < w; ++w2) {          // wave-uniform trip count
      r0 += tot[w2][lane][0]; r1 += tot[w2][lane][1];
    }
    #pragma unroll
    for (int j = 0; j < 32; ++j) {
      unsigned u = vb[j];
      bf16 h0 = f2b(r0), h1 = f2b(r1);
      unsigned pw = ((unsigned)*(unsigned short*)&h0) |
                    (((unsigned)*(unsigned short*)&h1) << 16);
      base[(size_t)(w * 32 + j) * 8192] = pw;
      r0 += bflo(u); r1 += bfhi(u);
    }
  } else {
    int idx = blockIdx.x - 1024;              // [0,32)
    int b = idx >> 2, ig = idx & 3;
    int i = ig * 64 + lane;
    float* base = zloc + (size_t)b * 32768 + i;
    float vb[32];
    #pragma unroll
    for (int j = 0; j < 32; ++j) vb[j] = base[(size_t)(w * 32 + j) * 256];
    float t = 0.f;
    #pragma unroll
    for (int j = 0; j < 32; ++j) t += vb[j];
    tot[w][lane][0] = t;
    __syncthreads();
    float r = 0.f;
    for (int w2 = 0; w2 < w; ++w2) r += tot[w2][lane][0];
    #pragma unroll
    for (int j = 0; j < 32; ++j) {
      float tt = vb[j];
      base[(size_t)(w * 32 + j) * 256] = r;
      r += tt;
    }
  }
}

// ---- k_out (unchanged from R6): phiQ in-kernel; 3 fused MFMA matmuls -------
// out[t] = (phiQ@Sp + tril(A)@V) / (phiQ.zp + rowsum(tril A) + eps)
__global__ __launch_bounds__(256)
__attribute__((amdgpu_waves_per_eu(1, 2))) void k_out(
    const void* __restrict__ q, const bf16* __restrict__ omb,
    const bf16* __restrict__ phiK, const void* __restrict__ v,
    const bf16* __restrict__ SlocT, const float* __restrict__ zloc,
    void* __restrict__ outp, const int* __restrict__ flag) {
  __shared__ short spT[64 * 264];   // phase A: pqs phiQ[t][i]; phase B: SpT[d][i]
  __shared__ short vTh[64 * 72];    // V^T hi bf16           9216 B
  __shared__ short vTl[64 * 72];    // V^T lo bf16           9216 B
  __shared__ short aT[64 * 72];     // masked A[t][tau]      9216 B

  int isf32 = *flag;
  int chunk = blockIdx.x;
  size_t tok0 = (size_t)chunk * 64;
  int tid = threadIdx.x;
  int lane = tid & 63;
  int li = lane & 15;
  int quad = lane >> 4;
  int w = __builtin_amdgcn_readfirstlane(tid >> 6);  // wave id = m-tile
  int m0 = w * 16;

  // ---- stage V^T split hi/lo (latency hidden under phase 1 compute) -------
  #pragma unroll
  for (int it = 0; it < 16; ++it) {
    int e = it * 256 + tid;
    int tau = e >> 6, d = e & 63;
    float vv = ldin(v, tok0 * 64 + e, isf32);
    bf16 h = f2b(vv);
    bf16 l = f2b(vv - b2f(h));
    vTh[d * 72 + tau] = *reinterpret_cast<short*>(&h);
    vTl[d * 72 + tau] = *reinterpret_cast<short*>(&l);
  }
  // ---- zero own above-diagonal A region (rows wave-private) ----------------
  {
    shortx4 z4 = {0, 0, 0, 0};
    int arow0 = m0 + li;
    for (int cc = (w + 1) * 16 + quad * 4; cc < 64; cc += 16)
      *reinterpret_cast<shortx4*>(&aT[arow0 * 72 + cc]) = z4;
  }

  // ---- phase 1: phiQ in-kernel ---------------------------------------------
  float dpart[4] = {0.f, 0.f, 0.f, 0.f};
  {
    short8 qa0, qa1;
    phi_load_a(q, tok0 + m0 + li, quad, isf32, qa0, qa1);
    floatx4 c[16];
    float mx[4];
    phi_mfma(omb, li, quad, qa0, qa1, c, mx);

    const float* zp = zloc + (size_t)chunk * 256;
    #pragma unroll
    for (int n0 = 0; n0 < 16; ++n0) {
      float zv = zp[n0 * 16 + li];
      #pragma unroll
      for (int r = 0; r < 4; ++r) {
        bf16 hv = f2b(__expf(c[n0][r] - mx[r]) * 0.0625f);  // 1/sqrt(256)
        short hb = *reinterpret_cast<short*>(&hv);
        spT[(m0 + quad * 4 + r) * 264 + n0 * 16 + li] = hb;  // own rows only
        dpart[r] += bflo((unsigned)(unsigned short)hb) * zv; // rounded bits
      }
    }
  }

  // ---- a1-frags from own pqs rows (no barrier: wave-private) ---------------
  const short* pqf = &spT[(m0 + li) * 264 + quad * 8];
  short8 a1[8];
  #pragma unroll
  for (int kk = 0; kk < 8; ++kk)
    a1[kk] = *reinterpret_cast<const short8*>(pqf + kk * 32);

  __syncthreads();   // all waves done reading pqs -> safe to overwrite spT

  // ---- re-stage spT with Sp (16B copies; latency hides under mm1) ----------
  {
    const short* src = (const short*)SlocT + (size_t)chunk * 16384;
    #pragma unroll
    for (int it = 0; it < 8; ++it) {
      int e = it * 256 + tid;
      int d = e >> 5, seg = e & 31;
      *reinterpret_cast<short8*>(&spT[d * 264 + seg * 8]) =
          *reinterpret_cast<const short8*>(src + d * 256 + seg * 8);
    }
  }

  // ---- mm1: A tiles, n0 <= w only ------------------------------------------
  floatx4 c1[4];
  #pragma unroll
  for (int n0 = 0; n0 < 4; ++n0) c1[n0] = (floatx4){0.f, 0.f, 0.f, 0.f};
  const short* pkb = (const short*)phiK + tok0 * 256;
  #pragma unroll
  for (int n0 = 0; n0 < 4; ++n0) {
    if (n0 <= w) {
      const short* bp = pkb + (size_t)(n0 * 16 + li) * 256 + quad * 8;
      floatx4 acc = c1[n0];
      #pragma unroll
      for (int kk = 0; kk < 8; ++kk) {
        short8 b = *reinterpret_cast<const short8*>(bp + kk * 32);
        acc = __builtin_amdgcn_mfma_f32_16x16x32_bf16(a1[kk], b, acc, 0, 0, 0);
      }
      c1[n0] = acc;
    }
  }

  // ---- tril mask + den rowsum partials + write bf16 A to own LDS rows ------
  #pragma unroll
  for (int n0 = 0; n0 < 4; ++n0) {
    if (n0 <= w) {
      int tau = n0 * 16 + li;
      #pragma unroll
      for (int r = 0; r < 4; ++r) {
        int t = m0 + quad * 4 + r;
        float val = (tau <= t) ? c1[n0][r] : 0.f;
        dpart[r] += val;
        bf16 hh = f2b(val);
        aT[t * 72 + tau] = *reinterpret_cast<short*>(&hh);
      }
    }
  }

  __syncthreads();   // SpT staged, vT ready (aT is wave-private)

  // ---- mm2 (phiQ @ Sp) + mm3 (trilA @ Vhi + trilA @ Vlo), shared acc -------
  floatx4 o[4];
  #pragma unroll
  for (int n0 = 0; n0 < 4; ++n0) o[n0] = (floatx4){0.f, 0.f, 0.f, 0.f};

  const short* arow = &aT[(m0 + li) * 72 + quad * 8];
  short8 a3_0 = *reinterpret_cast<const short8*>(arow);
  short8 a3_1 = *reinterpret_cast<const short8*>(arow + 32);

  #pragma unroll
  for (int n0 = 0; n0 < 4; ++n0) {
    floatx4 acc = o[n0];
    const short* sp = &spT[(n0 * 16 + li) * 264 + quad * 8];
    #pragma unroll
    for (int kk = 0; kk < 8; ++kk) {
      short8 b = *reinterpret_cast<const short8*>(sp + kk * 32);
      acc = __builtin_amdgcn_mfma_f32_16x16x32_bf16(a1[kk], b, acc, 0, 0, 0);
    }
    const short* vph = &vTh[(n0 * 16 + li) * 72 + quad * 8];
    const short* vpl = &vTl[(n0 * 16 + li) * 72 + quad * 8];
    short8 bh0 = *reinterpret_cast<const short8*>(vph);
    short8 bh1 = *reinterpret_cast<const short8*>(vph + 32);
    short8 bl0 = *reinterpret_cast<const short8*>(vpl);
    short8 bl1 = *reinterpret_cast<const short8*>(vpl + 32);
    acc = __builtin_amdgcn_mfma_f32_16x16x32_bf16(a3_0, bh0, acc, 0, 0, 0);
    acc = __builtin_amdgcn_mfma_f32_16x16x32_bf16(a3_1, bh1, acc, 0, 0, 0);
    acc = __builtin_amdgcn_mfma_f32_16x16x32_bf16(a3_0, bl0, acc, 0, 0, 0);
    acc = __builtin_amdgcn_mfma_f32_16x16x32_bf16(a3_1, bl1, acc, 0, 0, 0);
    o[n0] = acc;
  }

  // butterfly over the quad's 16 lanes: every lane gets full den for its rows
  #pragma unroll
  for (int mask = 1; mask < 16; mask <<= 1) {
    #pragma unroll
    for (int r = 0; r < 4; ++r) dpart[r] += __shfl_xor(dpart[r], mask, 64);
  }

  // ---- epilogue: out[t][d] = (out1+out2) / (den + eps) ---------------------
  #pragma unroll
  for (int r = 0; r < 4; ++r) {
    float rd = 1.f / (dpart[r] + 1e-6f);
    size_t obb = (tok0 + m0 + quad * 4 + r) * 64 + li;
    if (isf32) {
      float* op = (float*)outp + obb;
      #pragma unroll
      for (int n0 = 0; n0 < 4; ++n0) op[n0 * 16] = o[n0][r] * rd;
    } else {
      bf16* op = (bf16*)outp + obb;
      #pragma unroll
      for (int n0 = 0; n0 < 4; ++n0) op[n0 * 16] = f2b(o[n0][r] * rd);
    }
  }
}

extern "C" void kernel_launch(void* const* d_in, const int* in_sizes, int n_in,
                              void* d_out, int out_size, void* d_ws, size_t ws_size,
                              hipStream_t stream) {
  (void)in_sizes; (void)n_in; (void)out_size;
  if (ws_size < NEED_WS_BYTES) return;   // diagnostic guard

  const void* q = d_in[0];
  const void* k = d_in[1];
  const void* v = d_in[2];
  const void* omega = d_in[3];

  int*   flag = (int*)d_ws;
  float* wsf  = (float*)d_ws + 64;       // data starts 256 B in
  bf16*  omb  = (bf16*)wsf;              // 16384 bf16
  float* zloc = wsf + 131072;            // 1024*256 f32
  bf16*  Sloc = (bf16*)(wsf + 393216);   // 1024*256*64 bf16 (TRANSPOSED [d][i])
  bf16*  phiK = (bf16*)(wsf + 17170432); // 65536*256 bf16

  k_detect<<<1, 256, 0, stream>>>(q, flag);
  k_omega<<<64, 256, 0, stream>>>(omega, omb, flag);
  k_phik<<<1024, 256, 0, stream>>>(k, v, omb, phiK, Sloc, zloc, flag);
  k_prefix<<<1056, 256, 0, stream>>>(Sloc, zloc);
  k_out<<<1024, 256, 0, stream>>>(q, omb, phiK, v, Sloc, zloc, d_out, flag);
}

// Round 8
// 185.139 us; speedup vs baseline: 1.2684x; 1.0313x over previous
//
#include <hip/hip_runtime.h>
#include <hip/hip_bf16.h>

typedef __hip_bfloat16 bf16;
typedef __attribute__((ext_vector_type(8))) short short8;   // 8 bf16, 4 VGPRs
typedef __attribute__((ext_vector_type(4))) short shortx4;  // 4 bf16 (HIP owns "short4")
typedef __attribute__((ext_vector_type(4))) float floatx4;  // MFMA acc

// B=8, T=8192, D=64, M=256, chunk L=64, NCHUNK=1024, NTOK=65536
#define NEED_WS_BYTES 110625024ULL

__device__ __forceinline__ float b2f(bf16 x) { return __bfloat162float(x); }
__device__ __forceinline__ bf16  f2b(float x) { return __float2bfloat16(x); }
__device__ __forceinline__ float bflo(unsigned u) { return __uint_as_float(u << 16); }
__device__ __forceinline__ float bfhi(unsigned u) { return __uint_as_float(u & 0xffff0000u); }

// dtype-dispatched input load: isf32 ? f32 : bf16
__device__ __forceinline__ float ldin(const void* p, size_t i, int isf32) {
  return isf32 ? ((const float*)p)[i] : b2f(((const bf16*)p)[i]);
}

// f32 -> bf16 bits of (f * 0.125)
__device__ __forceinline__ short sb(float f) {
  bf16 h = f2b(f * 0.125f);
  return *reinterpret_cast<short*>(&h);
}
// bf16 bits -> bf16 bits of (x * 0.125) (exact exponent shift)
__device__ __forceinline__ short scale_b(short u) {
  float f = __uint_as_float(((unsigned)(unsigned short)u) << 16) * 0.125f;
  bf16 h = f2b(f);
  return *reinterpret_cast<short*>(&h);
}

// inline dtype detect on q's first 8KB (identical result in every block)
__device__ __forceinline__ int detect_f32(const void* q, int tid, int* cntp) {
  if (tid == 0) *cntp = 0;
  __syncthreads();
  const unsigned short* u = (const unsigned short*)q;
  int c = 0;
  for (int e = tid; e < 2048; e += 256) {
    unsigned short w = u[2 * e];
    int ex = (w >> 7) & 0xFF;
    if ((w & 0x7FFF) != 0 && (ex < 110 || ex > 140)) c++;
  }
  atomicAdd(cntp, c);
  __syncthreads();
  return (*cntp > 512) ? 1 : 0;
}

// ---- k_omega (R8): detect merged in; each block detects locally, block 0
// publishes flag for the later kernels. One launch saved. ---------------------
__global__ __launch_bounds__(256) void k_omega(const void* __restrict__ q,
                                               const void* __restrict__ omega,
                                               bf16* __restrict__ omb,
                                               int* __restrict__ flag) {
  __shared__ int cnt;
  int tid = threadIdx.x;
  int isf32 = detect_f32(q, tid, &cnt);
  if (blockIdx.x == 0 && tid == 0) *flag = isf32;
  int e = blockIdx.x * 256 + tid;
  omb[e] = f2b(ldin(omega, e, isf32));
}

// ---- shared phi helpers ----------------------------------------------------
// Layouts (m89/m91-verified): A[m=lane&15][k=quad*8+j], B[n=lane&15][k=quad*8+j],
// C: col=lane&15 (n-dim), row=quad*4+reg (m-dim).
__device__ __forceinline__ void phi_load_a(const void* src, size_t row, int quad,
                                           int isf32, short8& a0, short8& a1) {
  if (isf32) {
    const float* xr = (const float*)src + row * 64;
    float4 f0 = *reinterpret_cast<const float4*>(xr + quad * 8);
    float4 f1 = *reinterpret_cast<const float4*>(xr + quad * 8 + 4);
    float4 f2 = *reinterpret_cast<const float4*>(xr + 32 + quad * 8);
    float4 f3 = *reinterpret_cast<const float4*>(xr + 32 + quad * 8 + 4);
    a0[0] = sb(f0.x); a0[1] = sb(f0.y); a0[2] = sb(f0.z); a0[3] = sb(f0.w);
    a0[4] = sb(f1.x); a0[5] = sb(f1.y); a0[6] = sb(f1.z); a0[7] = sb(f1.w);
    a1[0] = sb(f2.x); a1[1] = sb(f2.y); a1[2] = sb(f2.z); a1[3] = sb(f2.w);
    a1[4] = sb(f3.x); a1[5] = sb(f3.y); a1[6] = sb(f3.z); a1[7] = sb(f3.w);
  } else {
    const short* xr = (const short*)src + row * 64;
    short8 r0 = *reinterpret_cast<const short8*>(xr + quad * 8);
    short8 r1 = *reinterpret_cast<const short8*>(xr + 32 + quad * 8);
    #pragma unroll
    for (int j = 0; j < 8; ++j) { a0[j] = scale_b(r0[j]); a1[j] = scale_b(r1[j]); }
  }
}

__device__ __forceinline__ void phi_mfma(const bf16* omb, int li, int quad,
                                         const short8& a0, const short8& a1,
                                         floatx4* c, float* mx) {
  #pragma unroll
  for (int n0 = 0; n0 < 16; ++n0) {
    const short* bp = (const short*)omb + (size_t)(n0 * 16 + li) * 64 + quad * 8;
    short8 b0 = *reinterpret_cast<const short8*>(bp);
    short8 b1 = *reinterpret_cast<const short8*>(bp + 32);
    floatx4 acc = {0.f, 0.f, 0.f, 0.f};
    acc = __builtin_amdgcn_mfma_f32_16x16x32_bf16(a0, b0, acc, 0, 0, 0);
    acc = __builtin_amdgcn_mfma_f32_16x16x32_bf16(a1, b1, acc, 0, 0, 0);
    c[n0] = acc;
  }
  #pragma unroll
  for (int r = 0; r < 4; ++r) {
    float m = c[0][r];
    #pragma unroll
    for (int n0 = 1; n0 < 16; ++n0) m = fmaxf(m, c[n0][r]);
    mx[r] = m;
  }
  #pragma unroll
  for (int mask = 1; mask < 16; mask <<= 1) {
    #pragma unroll
    for (int r = 0; r < 4; ++r) mx[r] = fmaxf(mx[r], __shfl_xor(mx[r], mask, 64));
  }
}

// ---- k_phik: phiK + fused S^T/z (unchanged from R7) ------------------------
__global__ __launch_bounds__(256)
__attribute__((amdgpu_waves_per_eu(1, 3))) void k_phik(
    const void* __restrict__ k, const void* __restrict__ v,
    const bf16* __restrict__ omb, bf16* __restrict__ phiK,
    bf16* __restrict__ SlocT, float* __restrict__ zloc,
    const int* __restrict__ flag) {
  __shared__ short pkT[256 * 64];    // 32768 B  phiK^T [i][t], chunk-swizzled
  __shared__ short vTh[64 * 72];     //  9216 B  V^T hi
  __shared__ short vTl[64 * 72];     //  9216 B  V^T lo

  int isf32 = *flag;
  int tid = threadIdx.x;
  size_t tok0 = (size_t)blockIdx.x * 64;
  int li = tid & 15;
  int quad = (tid >> 4) & 3;
  int w = tid >> 6;
  int m0 = w * 16;
  size_t row = tok0 + m0 + li;

  // ---- stage V^T hi/lo -----------------------------------------------------
  #pragma unroll
  for (int it = 0; it < 16; ++it) {
    int e = it * 256 + tid;
    int tau = e >> 6, d = e & 63;
    float vv = ldin(v, tok0 * 64 + e, isf32);
    bf16 h = f2b(vv);
    bf16 l = f2b(vv - b2f(h));
    vTh[d * 72 + tau] = *reinterpret_cast<short*>(&h);
    vTl[d * 72 + tau] = *reinterpret_cast<short*>(&l);
  }

  // ---- phi compute ---------------------------------------------------------
  short8 a0, a1;
  phi_load_a(k, row, quad, isf32, a0, a1);
  floatx4 c[16];
  float mx[4];
  phi_mfma(omb, li, quad, a0, a1, c, mx);

  // ---- exp -> phiK global scatter + swizzled pkT ---------------------------
  #pragma unroll
  for (int n0 = 0; n0 < 16; ++n0) {
    #pragma unroll
    for (int r = 0; r < 4; ++r) {
      bf16 hv = f2b(__expf(c[n0][r] - mx[r]) * 0.0625f);  // 1/sqrt(256)
      short hb = *reinterpret_cast<short*>(&hv);
      int i = n0 * 16 + li;
      int t = m0 + quad * 4 + r;
      ((short*)phiK)[(tok0 + t) * 256 + i] = hb;            // 4x32B segs/instr
      int cch = (t >> 3) ^ (i & 7);                         // XOR chunk swizzle
      pkT[i * 64 + cch * 8 + (t & 7)] = hb;
    }
  }

  __syncthreads();   // pkT, vTh/vTl ready

  // ---- z[i] = rowsum of pkT row i (same rounded values as stored) ----------
  {
    int i2 = tid;
    float zz = 0.f;
    #pragma unroll
    for (int c8 = 0; c8 < 8; ++c8) {
      short8 vv8 = *reinterpret_cast<const short8*>(
          &pkT[i2 * 64 + (c8 ^ (i2 & 7)) * 8]);
      #pragma unroll
      for (int j = 0; j < 8; ++j) zz += bflo((unsigned)(unsigned short)vv8[j]);
    }
    zloc[(size_t)blockIdx.x * 256 + i2] = zz;
  }

  // ---- S GEMM: wave w -> features [w*64, w*64+64), all d ------------------
  int wbase = w * 64;
  floatx4 sa[4][4];
  #pragma unroll
  for (int mt = 0; mt < 4; ++mt)
    #pragma unroll
    for (int n0 = 0; n0 < 4; ++n0) sa[mt][n0] = (floatx4){0.f, 0.f, 0.f, 0.f};

  #pragma unroll
  for (int h = 0; h < 2; ++h) {
    short8 Ah[4], Al[4];
    #pragma unroll
    for (int mt = 0; mt < 4; ++mt) {
      Ah[mt] = *reinterpret_cast<const short8*>(
          &vTh[(mt * 16 + li) * 72 + h * 32 + quad * 8]);
      Al[mt] = *reinterpret_cast<const short8*>(
          &vTl[(mt * 16 + li) * 72 + h * 32 + quad * 8]);
    }
    #pragma unroll
    for (int n0 = 0; n0 < 4; ++n0) {
      int crow = wbase + n0 * 16 + li;
      int cc = (h * 4 + quad) ^ (li & 7);
      short8 Bq = *reinterpret_cast<const short8*>(&pkT[crow * 64 + cc * 8]);
      #pragma unroll
      for (int mt = 0; mt < 4; ++mt) {
        sa[mt][n0] =
            __builtin_amdgcn_mfma_f32_16x16x32_bf16(Ah[mt], Bq, sa[mt][n0], 0, 0, 0);
        sa[mt][n0] =
            __builtin_amdgcn_mfma_f32_16x16x32_bf16(Al[mt], Bq, sa[mt][n0], 0, 0, 0);
      }
    }
  }

  // ---- store S^T (bf16) ----------------------------------------------------
  bf16* Sb = SlocT + (size_t)blockIdx.x * 16384;
  #pragma unroll
  for (int mt = 0; mt < 4; ++mt)
    #pragma unroll
    for (int n0 = 0; n0 < 4; ++n0)
      #pragma unroll
      for (int r = 0; r < 4; ++r)
        Sb[(mt * 16 + quad * 4 + r) * 256 + wbase + n0 * 16 + li] =
            f2b(sa[mt][n0][r]);
}

// ---- k_prefix: merged hierarchical exclusive scans (unchanged from R7) -----
__global__ __launch_bounds__(256) void k_prefix(bf16* __restrict__ SlocT,
                                                float* __restrict__ zloc) {
  __shared__ float tot[4][64][2];
  int tid = threadIdx.x;
  int lane = tid & 63;
  int w = tid >> 6;
  if (blockIdx.x < 1024) {
    int b = blockIdx.x >> 7, g = blockIdx.x & 127;
    int p = g * 64 + lane;                    // short2 column [0,8192)
    unsigned* base = (unsigned*)(SlocT + (size_t)b * 2097152) + p;
    unsigned vb[32];
    #pragma unroll
    for (int j = 0; j < 32; ++j) vb[j] = base[(size_t)(w * 32 + j) * 8192];
    float t0 = 0.f, t1 = 0.f;
    #pragma unroll
    for (int j = 0; j < 32; ++j) { t0 += bflo(vb[j]); t1 += bfhi(vb[j]); }
    tot[w][lane][0] = t0; tot[w][lane][1] = t1;
    __syncthreads();
    float r0 = 0.f, r1 = 0.f;
    for (int w2 = 0; w2 < w; ++w2) {          // wave-uniform trip count
      r0 += tot[w2][lane][0]; r1 += tot[w2][lane][1];
    }
    #pragma unroll
    for (int j = 0; j < 32; ++j) {
      unsigned u = vb[j];
      bf16 h0 = f2b(r0), h1 = f2b(r1);
      unsigned pw = ((unsigned)*(unsigned short*)&h0) |
                    (((unsigned)*(unsigned short*)&h1) << 16);
      base[(size_t)(w * 32 + j) * 8192] = pw;
      r0 += bflo(u); r1 += bfhi(u);
    }
  } else {
    int idx = blockIdx.x - 1024;              // [0,32)
    int b = idx >> 2, ig = idx & 3;
    int i = ig * 64 + lane;
    float* base = zloc + (size_t)b * 32768 + i;
    float vb[32];
    #pragma unroll
    for (int j = 0; j < 32; ++j) vb[j] = base[(size_t)(w * 32 + j) * 256];
    float t = 0.f;
    #pragma unroll
    for (int j = 0; j < 32; ++j) t += vb[j];
    tot[w][lane][0] = t;
    __syncthreads();
    float r = 0.f;
    for (int w2 = 0; w2 < w; ++w2) r += tot[w2][lane][0];
    #pragma unroll
    for (int j = 0; j < 32; ++j) {
      float tt = vb[j];
      base[(size_t)(w * 32 + j) * 256] = r;
      r += tt;
    }
  }
}

// ---- k_out (R8): vTl dropped -> LDS 52224 B -> 3 blocks/CU -----------------
// out[t] = (phiQ@Sp + tril(A)@V) / (phiQ.zp + rowsum(tril A) + eps)
// mm3 uses bf16 V only (A is already bf16-rounded; V's extra 2^-9 relative
// error predicted absmax ~0.02). TRIPWIRE: absmax > 0.03 => revert vTl.
// waves_per_eu(1,3): 12 waves/CU; VGPR 112 <= 170 so no demotion risk.
__global__ __launch_bounds__(256)
__attribute__((amdgpu_waves_per_eu(1, 3))) void k_out(
    const void* __restrict__ q, const bf16* __restrict__ omb,
    const bf16* __restrict__ phiK, const void* __restrict__ v,
    const bf16* __restrict__ SlocT, const float* __restrict__ zloc,
    void* __restrict__ outp, const int* __restrict__ flag) {
  __shared__ short spT[64 * 264];   // phase A: pqs phiQ[t][i]; phase B: SpT[d][i]
  __shared__ short vTh[64 * 72];    // V^T bf16              9216 B
  __shared__ short aT[64 * 72];     // masked A[t][tau]      9216 B

  int isf32 = *flag;
  int chunk = blockIdx.x;
  size_t tok0 = (size_t)chunk * 64;
  int tid = threadIdx.x;
  int lane = tid & 63;
  int li = lane & 15;
  int quad = lane >> 4;
  int w = __builtin_amdgcn_readfirstlane(tid >> 6);  // wave id = m-tile
  int m0 = w * 16;

  // ---- stage V^T (latency hidden under phase 1 compute) --------------------
  #pragma unroll
  for (int it = 0; it < 16; ++it) {
    int e = it * 256 + tid;
    int tau = e >> 6, d = e & 63;
    bf16 h = f2b(ldin(v, tok0 * 64 + e, isf32));
    vTh[d * 72 + tau] = *reinterpret_cast<short*>(&h);
  }
  // ---- zero own above-diagonal A region (rows wave-private) ----------------
  {
    shortx4 z4 = {0, 0, 0, 0};
    int arow0 = m0 + li;
    for (int cc = (w + 1) * 16 + quad * 4; cc < 64; cc += 16)
      *reinterpret_cast<shortx4*>(&aT[arow0 * 72 + cc]) = z4;
  }

  // ---- phase 1: phiQ in-kernel ---------------------------------------------
  float dpart[4] = {0.f, 0.f, 0.f, 0.f};
  {
    short8 qa0, qa1;
    phi_load_a(q, tok0 + m0 + li, quad, isf32, qa0, qa1);
    floatx4 c[16];
    float mx[4];
    phi_mfma(omb, li, quad, qa0, qa1, c, mx);

    const float* zp = zloc + (size_t)chunk * 256;
    #pragma unroll
    for (int n0 = 0; n0 < 16; ++n0) {
      float zv = zp[n0 * 16 + li];
      #pragma unroll
      for (int r = 0; r < 4; ++r) {
        bf16 hv = f2b(__expf(c[n0][r] - mx[r]) * 0.0625f);  // 1/sqrt(256)
        short hb = *reinterpret_cast<short*>(&hv);
        spT[(m0 + quad * 4 + r) * 264 + n0 * 16 + li] = hb;  // own rows only
        dpart[r] += bflo((unsigned)(unsigned short)hb) * zv; // rounded bits
      }
    }
  }

  // ---- a1-frags from own pqs rows (no barrier: wave-private) ---------------
  const short* pqf = &spT[(m0 + li) * 264 + quad * 8];
  short8 a1[8];
  #pragma unroll
  for (int kk = 0; kk < 8; ++kk)
    a1[kk] = *reinterpret_cast<const short8*>(pqf + kk * 32);

  __syncthreads();   // all waves done reading pqs -> safe to overwrite spT

  // ---- re-stage spT with Sp (16B copies; latency hides under mm1) ----------
  {
    const short* src = (const short*)SlocT + (size_t)chunk * 16384;
    #pragma unroll
    for (int it = 0; it < 8; ++it) {
      int e = it * 256 + tid;
      int d = e >> 5, seg = e & 31;
      *reinterpret_cast<short8*>(&spT[d * 264 + seg * 8]) =
          *reinterpret_cast<const short8*>(src + d * 256 + seg * 8);
    }
  }

  // ---- mm1: A tiles, n0 <= w only ------------------------------------------
  floatx4 c1[4];
  #pragma unroll
  for (int n0 = 0; n0 < 4; ++n0) c1[n0] = (floatx4){0.f, 0.f, 0.f, 0.f};
  const short* pkb = (const short*)phiK + tok0 * 256;
  #pragma unroll
  for (int n0 = 0; n0 < 4; ++n0) {
    if (n0 <= w) {
      const short* bp = pkb + (size_t)(n0 * 16 + li) * 256 + quad * 8;
      floatx4 acc = c1[n0];
      #pragma unroll
      for (int kk = 0; kk < 8; ++kk) {
        short8 b = *reinterpret_cast<const short8*>(bp + kk * 32);
        acc = __builtin_amdgcn_mfma_f32_16x16x32_bf16(a1[kk], b, acc, 0, 0, 0);
      }
      c1[n0] = acc;
    }
  }

  // ---- tril mask + den rowsum partials + write bf16 A to own LDS rows ------
  #pragma unroll
  for (int n0 = 0; n0 < 4; ++n0) {
    if (n0 <= w) {
      int tau = n0 * 16 + li;
      #pragma unroll
      for (int r = 0; r < 4; ++r) {
        int t = m0 + quad * 4 + r;
        float val = (tau <= t) ? c1[n0][r] : 0.f;
        dpart[r] += val;
        bf16 hh = f2b(val);
        aT[t * 72 + tau] = *reinterpret_cast<short*>(&hh);
      }
    }
  }

  __syncthreads();   // SpT staged, vTh ready (aT is wave-private)

  // ---- mm2 (phiQ @ Sp) + mm3 (trilA @ V), shared acc -----------------------
  floatx4 o[4];
  #pragma unroll
  for (int n0 = 0; n0 < 4; ++n0) o[n0] = (floatx4){0.f, 0.f, 0.f, 0.f};

  const short* arow = &aT[(m0 + li) * 72 + quad * 8];
  short8 a3_0 = *reinterpret_cast<const short8*>(arow);
  short8 a3_1 = *reinterpret_cast<const short8*>(arow + 32);

  #pragma unroll
  for (int n0 = 0; n0 < 4; ++n0) {
    floatx4 acc = o[n0];
    const short* sp = &spT[(n0 * 16 + li) * 264 + quad * 8];
    #pragma unroll
    for (int kk = 0; kk < 8; ++kk) {
      short8 b = *reinterpret_cast<const short8*>(sp + kk * 32);
      acc = __builtin_amdgcn_mfma_f32_16x16x32_bf16(a1[kk], b, acc, 0, 0, 0);
    }
    const short* vph = &vTh[(n0 * 16 + li) * 72 + quad * 8];
    short8 bh0 = *reinterpret_cast<const short8*>(vph);
    short8 bh1 = *reinterpret_cast<const short8*>(vph + 32);
    acc = __builtin_amdgcn_mfma_f32_16x16x32_bf16(a3_0, bh0, acc, 0, 0, 0);
    acc = __builtin_amdgcn_mfma_f32_16x16x32_bf16(a3_1, bh1, acc, 0, 0, 0);
    o[n0] = acc;
  }

  // butterfly over the quad's 16 lanes: every lane gets full den for its rows
  #pragma unroll
  for (int mask = 1; mask < 16; mask <<= 1) {
    #pragma unroll
    for (int r = 0; r < 4; ++r) dpart[r] += __shfl_xor(dpart[r], mask, 64);
  }

  // ---- epilogue: out[t][d] = (out1+out2) / (den + eps) ---------------------
  #pragma unroll
  for (int r = 0; r < 4; ++r) {
    float rd = 1.f / (dpart[r] + 1e-6f);
    size_t obb = (tok0 + m0 + quad * 4 + r) * 64 + li;
    if (isf32) {
      float* op = (float*)outp + obb;
      #pragma unroll
      for (int n0 = 0; n0 < 4; ++n0) op[n0 * 16] = o[n0][r] * rd;
    } else {
      bf16* op = (bf16*)outp + obb;
      #pragma unroll
      for (int n0 = 0; n0 < 4; ++n0) op[n0 * 16] = f2b(o[n0][r] * rd);
    }
  }
}

extern "C" void kernel_launch(void* const* d_in, const int* in_sizes, int n_in,
                              void* d_out, int out_size, void* d_ws, size_t ws_size,
                              hipStream_t stream) {
  (void)in_sizes; (void)n_in; (void)out_size;
  if (ws_size < NEED_WS_BYTES) return;   // diagnostic guard

  const void* q = d_in[0];
  const void* k = d_in[1];
  const void* v = d_in[2];
  const void* omega = d_in[3];

  int*   flag = (int*)d_ws;
  float* wsf  = (float*)d_ws + 64;       // data starts 256 B in
  bf16*  omb  = (bf16*)wsf;              // 16384 bf16
  float* zloc = wsf + 131072;            // 1024*256 f32
  bf16*  Sloc = (bf16*)(wsf + 393216);   // 1024*256*64 bf16 (TRANSPOSED [d][i])
  bf16*  phiK = (bf16*)(wsf + 17170432); // 65536*256 bf16

  k_omega<<<64, 256, 0, stream>>>(q, omega, omb, flag);
  k_phik<<<1024, 256, 0, stream>>>(k, v, omb, phiK, Sloc, zloc, flag);
  k_prefix<<<1056, 256, 0, stream>>>(Sloc, zloc);
  k_out<<<1024, 256, 0, stream>>>(q, omb, phiK, v, Sloc, zloc, d_out, flag);
}